// Round 7
// baseline (225.249 us; speedup 1.0000x reference)
//
#include <hip/hip_runtime.h>
#include <math.h>

#define BB   32
#define HH   56
#define WWI  56
#define CC   96
#define NHD  3
#define WSZ  7
#define SHF  3
#define NTK  49
#define NWIN 64
#define HDM  32
#define TOT  (BB*HH*WWI)               // 100352
#define QKSCALE 0.17677669529663687f
#define LEPS 1e-3f

typedef __attribute__((ext_vector_type(8))) short s8v;   // 8 bf16 (4 VGPRs)
typedef __attribute__((ext_vector_type(4))) float fx4;   // 4 fp32
typedef unsigned long long ull_t;

#define MFMA16(a,b,c) __builtin_amdgcn_mfma_f32_16x16x32_bf16((a),(b),(c),0,0,0)

__device__ __forceinline__ unsigned short f2bf(float f) {
    union { float f; unsigned u; } v; v.f = f;
    unsigned r = v.u + 0x7FFFu + ((v.u >> 16) & 1u);
    return (unsigned short)(r >> 16);
}

// sigmoid-form gelu: |err vs exact-erf gelu| <~2e-3, ~8 VALU ops vs ~28 for erff
__device__ __forceinline__ float gelu_t(float x) {
    float x3 = x * x * x;
    float z = -1.5957691216f * fmaf(0.044715f, x3, x);
    return x * __builtin_amdgcn_rcpf(1.f + __expf(z));
}

// windowed token id -> original flat token id (roll(-3,-3) + window partition)
__device__ __forceinline__ int wtok_to_orig(int wt) {
    int win = wt / NTK;
    int p   = wt - win * NTK;
    int b   = win >> 6;
    int w   = win & 63;
    int wi = w >> 3, wj = w & 7;
    int pi = p / WSZ, pj = p - pi * WSZ;
    int r = wi * WSZ + pi + SHF; if (r >= HH) r -= HH;
    int c = wj * WSZ + pj + SHF; if (c >= WWI) c -= WWI;
    return b * (HH * WWI) + r * WWI + c;
}

// ---------- P0: weight transpose/bf16 + combined bias+mask table ----------
// wsw layout: qwt[288][96] | pwt[96][96] | w1t[384][96] | w2t[96][384] |
//             (as float, 4B-aligned) BM[4 cls][3 h][49 m][64 n]
extern "C" __global__ void p0_prep(const float* __restrict__ qw, const float* __restrict__ pw,
                                   const float* __restrict__ w1, const float* __restrict__ w2,
                                   const float* __restrict__ btab,
                                   unsigned short* __restrict__ wsw)
{
    int i = blockIdx.x * 256 + threadIdx.x;
    if (i < 27648) {                       // qwt[288][96]
        int n = i / 96, k = i - n * 96;
        wsw[i] = f2bf(qw[k * 288 + n]);
    } else if (i < 36864) {                // pwt[96][96]
        int j = i - 27648; int n = j / 96, k = j - n * 96;
        wsw[i] = f2bf(pw[k * 96 + n]);
    } else if (i < 73728) {                // w1t[384][96]
        int j = i - 36864; int n = j / 96, k = j - n * 96;
        wsw[i] = f2bf(w1[k * 384 + n]);
    } else if (i < 110592) {               // w2t[96][384]
        int j = i - 73728; int n = j / 384, k = j - n * 384;
        wsw[i] = f2bf(w2[k * 96 + n]);
    } else if (i < 148224) {               // BM table (fp32)
        float* bm = (float*)(wsw + 110592);
        int j = i - 110592;
        int n = j & 63, mh = j >> 6;
        int m = mh % 49, t = mh / 49;
        int hd = t % 3, cls = t / 3;       // cls = (wi==7)*2 + (wj==7)
        float val = 0.f;
        if (n < 49) {
            int it = m / 7, jt = m - it * 7;
            int iu = n / 7, ju = n - iu * 7;
            int li  = (cls & 2) ? (it < 4 ? 1 : 2) : 0;
            int lj  = (cls & 1) ? (jt < 4 ? 1 : 2) : 0;
            int lui = (cls & 2) ? (iu < 4 ? 1 : 2) : 0;
            int luj = (cls & 1) ? (ju < 4 ? 1 : 2) : 0;
            int bidx = (jt - ju + 6) * 13 + (it - iu + 6);
            val = btab[bidx * 3 + hd] + ((li*3+lj) == (lui*3+luj) ? 0.f : -100.f);
        }
        bm[j] = val;
    }
}

// ---------- K1: gather + LN1 + QKV MFMA GEMM -> qkv[TOT][288] fp32 ----------
// B-frags read directly from global (weights are L1/L2-resident); LDS holds
// only Hn -> 13.3 KB, no barriers inside the ck loop.
#define LDH 104
extern "C" __global__ void __launch_bounds__(256, 4) k1_qkv(
    const float* __restrict__ x, const float* __restrict__ g1, const float* __restrict__ b1,
    const unsigned short* __restrict__ qwt, const float* __restrict__ qb,
    float* __restrict__ qkv)
{
    __shared__ unsigned short Hn[64 * LDH];
    const int tid = threadIdx.x, wave = tid >> 6, lane = tid & 63;
    const int l15 = lane & 15, g4 = lane >> 4;
    const int blk = blockIdx.x;

    { // LN1: 4 lanes per token
        const int tl = tid >> 2, q4 = tid & 3;
        const int orig = wtok_to_orig(blk * 64 + tl);
        const float* row = x + (size_t)orig * CC + q4 * 24;
        float h[24];
        #pragma unroll
        for (int j = 0; j < 6; ++j) {
            fx4 v = *reinterpret_cast<const fx4*>(row + 4 * j);
            h[4*j]=v.x; h[4*j+1]=v.y; h[4*j+2]=v.z; h[4*j+3]=v.w;
        }
        float s = 0.f, s2 = 0.f;
        #pragma unroll
        for (int j = 0; j < 24; ++j) { s += h[j]; s2 = fmaf(h[j], h[j], s2); }
        s  += __shfl_xor(s, 1);  s  += __shfl_xor(s, 2);
        s2 += __shfl_xor(s2, 1); s2 += __shfl_xor(s2, 2);
        const float mu = s * (1.f/CC);
        const float rs = rsqrtf(s2 * (1.f/CC) - mu * mu + LEPS);
        unsigned short t[24];
        #pragma unroll
        for (int j = 0; j < 24; ++j) {
            int c = q4 * 24 + j;
            t[j] = f2bf((h[j] - mu) * rs * g1[c] + b1[c]);
        }
        #pragma unroll
        for (int j = 0; j < 6; ++j) {
            ull_t pk = (ull_t)t[4*j] | ((ull_t)t[4*j+1] << 16) |
                       ((ull_t)t[4*j+2] << 32) | ((ull_t)t[4*j+3] << 48);
            *reinterpret_cast<ull_t*>(&Hn[tl * LDH + q4 * 24 + 4*j]) = pk;
        }
    }
    __syncthreads();

    for (int ck = 0; ck < 3; ++ck) {
        fx4 acc[6];
        #pragma unroll
        for (int nt = 0; nt < 6; ++nt) acc[nt] = (fx4){0.f,0.f,0.f,0.f};
        #pragma unroll
        for (int ks = 0; ks < 3; ++ks) {
            s8v a = *reinterpret_cast<const s8v*>(&Hn[(wave*16 + l15)*LDH + ks*32 + g4*8]);
            #pragma unroll
            for (int nt = 0; nt < 6; ++nt) {
                s8v b = *reinterpret_cast<const s8v*>(
                    &qwt[(size_t)(ck*96 + nt*16 + l15) * 96 + ks*32 + g4*8]);
                acc[nt] = MFMA16(a, b, acc[nt]);
            }
        }
        const int rowb = blk * 64 + wave * 16 + g4 * 4;
        #pragma unroll
        for (int nt = 0; nt < 6; ++nt) {
            const int col = ck * 96 + nt * 16 + l15;
            const float qbc = qb[col];
            #pragma unroll
            for (int r = 0; r < 4; ++r)
                qkv[(size_t)(rowb + r) * 288 + col] = acc[nt][r] + qbc;
        }
    }
}

// ---------- K2: MFMA attention, 1 wave = 1 (window, head) ----------
extern "C" __global__ void __launch_bounds__(64, 2) k2_attn(
    float* __restrict__ qkv, const float* __restrict__ bm)
{
    __shared__ unsigned short P[64][72];   // 9216 B
    const int lane = threadIdx.x;
    const int l15 = lane & 15, g4 = lane >> 4;
    const int task = blockIdx.x;
    const int win = task / 3, h = task - win * 3;
    const int g0  = win * NTK;
    const int w   = win & 63;
    const int cls = (((w >> 3) == 7) ? 2 : 0) + (((w & 7) == 7) ? 1 : 0);
    const float* BMh = bm + ((size_t)(cls * 3 + h)) * 49 * 64;

    s8v aq[4], bk[4];
    #pragma unroll
    for (int mt = 0; mt < 4; ++mt) {
        int tok = mt * 16 + l15; if (tok > 48) tok = 48;
        const float* qp = &qkv[(size_t)(g0 + tok) * 288 + h * HDM + g4 * 8];
        fx4 v0 = *reinterpret_cast<const fx4*>(qp);
        fx4 v1 = *reinterpret_cast<const fx4*>(qp + 4);
        union { s8v v; unsigned short u[8]; } pa;
        pa.u[0]=f2bf(v0.x*QKSCALE); pa.u[1]=f2bf(v0.y*QKSCALE);
        pa.u[2]=f2bf(v0.z*QKSCALE); pa.u[3]=f2bf(v0.w*QKSCALE);
        pa.u[4]=f2bf(v1.x*QKSCALE); pa.u[5]=f2bf(v1.y*QKSCALE);
        pa.u[6]=f2bf(v1.z*QKSCALE); pa.u[7]=f2bf(v1.w*QKSCALE);
        aq[mt] = pa.v;
        const float* kp = &qkv[(size_t)(g0 + tok) * 288 + 96 + h * HDM + g4 * 8];
        fx4 k0 = *reinterpret_cast<const fx4*>(kp);
        fx4 k1 = *reinterpret_cast<const fx4*>(kp + 4);
        union { s8v v; unsigned short u[8]; } pb;
        pb.u[0]=f2bf(k0.x); pb.u[1]=f2bf(k0.y); pb.u[2]=f2bf(k0.z); pb.u[3]=f2bf(k0.w);
        pb.u[4]=f2bf(k1.x); pb.u[5]=f2bf(k1.y); pb.u[6]=f2bf(k1.z); pb.u[7]=f2bf(k1.w);
        bk[mt] = pb.v;
    }

    fx4 sc[4][4];
    #pragma unroll
    for (int mt = 0; mt < 4; ++mt)
        #pragma unroll
        for (int nt = 0; nt < 4; ++nt)
            sc[mt][nt] = MFMA16(aq[mt], bk[nt], ((fx4){0.f,0.f,0.f,0.f}));

    #pragma unroll
    for (int mt = 0; mt < 4; ++mt) {
        #pragma unroll
        for (int r = 0; r < 4; ++r) {
            const int m = mt * 16 + g4 * 4 + r;
            const int mc = m > 48 ? 48 : m;
            float rs1 = 0.f;
            #pragma unroll
            for (int nt = 0; nt < 4; ++nt) {
                const int n = nt * 16 + l15;
                float s = sc[mt][nt][r] + BMh[mc * 64 + n];
                float e = (n < NTK) ? __expf(s) : 0.f;
                sc[mt][nt][r] = e;
                rs1 += e;
            }
            rs1 += __shfl_xor(rs1, 1); rs1 += __shfl_xor(rs1, 2);
            rs1 += __shfl_xor(rs1, 4); rs1 += __shfl_xor(rs1, 8);
            const float iv1 = 1.f / rs1;
            float rs2 = 0.f;
            #pragma unroll
            for (int nt = 0; nt < 4; ++nt) {
                const int n = nt * 16 + l15;
                float e2 = (n < NTK) ? __expf(sc[mt][nt][r] * iv1) : 0.f;
                sc[mt][nt][r] = e2;
                rs2 += e2;
            }
            rs2 += __shfl_xor(rs2, 1); rs2 += __shfl_xor(rs2, 2);
            rs2 += __shfl_xor(rs2, 4); rs2 += __shfl_xor(rs2, 8);
            const float iv2 = 1.f / rs2;
            #pragma unroll
            for (int nt = 0; nt < 4; ++nt)
                P[m][nt * 16 + l15] = f2bf(sc[mt][nt][r] * iv2);
        }
    }
    __syncthreads();

    fx4 oc[4][2];
    #pragma unroll
    for (int mt = 0; mt < 4; ++mt) { oc[mt][0] = (fx4){0.f,0.f,0.f,0.f}; oc[mt][1] = (fx4){0.f,0.f,0.f,0.f}; }
    #pragma unroll
    for (int ks = 0; ks < 2; ++ks) {
        s8v vb[2];
        #pragma unroll
        for (int nt = 0; nt < 2; ++nt) {
            union { s8v v; unsigned short u[8]; } pv;
            #pragma unroll
            for (int j = 0; j < 8; ++j) {
                int tok = ks * 32 + g4 * 8 + j; if (tok > 48) tok = 48;
                pv.u[j] = f2bf(qkv[(size_t)(g0 + tok) * 288 + 192 + h * HDM + nt * 16 + l15]);
            }
            vb[nt] = pv.v;
        }
        #pragma unroll
        for (int mt = 0; mt < 4; ++mt) {
            s8v pa = *reinterpret_cast<const s8v*>(&P[mt * 16 + l15][ks * 32 + g4 * 8]);
            oc[mt][0] = MFMA16(pa, vb[0], oc[mt][0]);
            oc[mt][1] = MFMA16(pa, vb[1], oc[mt][1]);
        }
    }
    #pragma unroll
    for (int mt = 0; mt < 4; ++mt) {
        #pragma unroll
        for (int r = 0; r < 4; ++r) {
            const int m = mt * 16 + g4 * 4 + r;
            if (m < NTK) {
                qkv[(size_t)(g0 + m) * 288 + h * HDM + l15]      = oc[mt][0][r];
                qkv[(size_t)(g0 + m) * 288 + h * HDM + 16 + l15] = oc[mt][1][r];
            }
        }
    }
}

// ---------- K2b: proj MFMA GEMM + residual + un-shift scatter -> d_out ----------
// B-frags direct from global (pwt is L1/L2-resident); LDS = Ao only.
extern "C" __global__ void __launch_bounds__(256, 4) k2b_proj(
    const float* __restrict__ qkv, const unsigned short* __restrict__ pwt,
    const float* __restrict__ pb, const float* __restrict__ x, float* __restrict__ out)
{
    __shared__ unsigned short Ao[64 * LDH];
    const int tid = threadIdx.x, wave = tid >> 6, lane = tid & 63;
    const int l15 = lane & 15, g4 = lane >> 4;
    const int blk = blockIdx.x;

    {
        const int tl = tid >> 2, q4 = tid & 3;
        const float* row = qkv + (size_t)(blk * 64 + tl) * 288 + q4 * 24;
        unsigned short t[24];
        #pragma unroll
        for (int j = 0; j < 6; ++j) {
            fx4 v = *reinterpret_cast<const fx4*>(row + 4 * j);
            t[4*j]=f2bf(v.x); t[4*j+1]=f2bf(v.y); t[4*j+2]=f2bf(v.z); t[4*j+3]=f2bf(v.w);
        }
        #pragma unroll
        for (int j = 0; j < 6; ++j) {
            ull_t pk = (ull_t)t[4*j] | ((ull_t)t[4*j+1] << 16) |
                       ((ull_t)t[4*j+2] << 32) | ((ull_t)t[4*j+3] << 48);
            *reinterpret_cast<ull_t*>(&Ao[tl * LDH + q4 * 24 + 4*j]) = pk;
        }
    }
    __syncthreads();

    fx4 acc[6];
    #pragma unroll
    for (int nt = 0; nt < 6; ++nt) acc[nt] = (fx4){0.f,0.f,0.f,0.f};
    #pragma unroll
    for (int ks = 0; ks < 3; ++ks) {
        s8v a = *reinterpret_cast<const s8v*>(&Ao[(wave*16 + l15)*LDH + ks*32 + g4*8]);
        #pragma unroll
        for (int nt = 0; nt < 6; ++nt) {
            s8v b = *reinterpret_cast<const s8v*>(
                &pwt[(size_t)(nt*16 + l15) * 96 + ks*32 + g4*8]);
            acc[nt] = MFMA16(a, b, acc[nt]);
        }
    }
    int orig[4];
    #pragma unroll
    for (int r = 0; r < 4; ++r)
        orig[r] = wtok_to_orig(blk * 64 + wave * 16 + g4 * 4 + r);
    #pragma unroll
    for (int nt = 0; nt < 6; ++nt) {
        const int col = nt * 16 + l15;
        const float pbc = pb[col];
        #pragma unroll
        for (int r = 0; r < 4; ++r) {
            const size_t idx = (size_t)orig[r] * CC + col;
            out[idx] = acc[nt][r] + pbc + x[idx];
        }
    }
}

// ---------- K3: LN2 + fc1 + gelu^2 + fc2 + residual ----------
// Weights read direct from global (L1/L2-resident); LDS = Hn + Ac = 22.5 KB
// (was 49.6 -> 3 blocks/CU); sigmoid-form gelu (~8 ops vs ~28 for erff).
#define LDA 72
extern "C" __global__ void __launch_bounds__(256, 4) k3_mlp(
    float* __restrict__ xio, const float* __restrict__ g2, const float* __restrict__ b2,
    const unsigned short* __restrict__ w1t, const float* __restrict__ bf1,
    const unsigned short* __restrict__ w2t, const float* __restrict__ bf2)
{
    __shared__ unsigned short Hn[64 * LDH];   // 13312 B
    __shared__ unsigned short Ac[64 * LDA];   //  9216 B
    const int tid = threadIdx.x, wave = tid >> 6, lane = tid & 63;
    const int l15 = lane & 15, g4 = lane >> 4;
    const int blk = blockIdx.x;

    { // LN2
        const int tl = tid >> 2, q4 = tid & 3;
        const float* row = xio + (size_t)(blk * 64 + tl) * CC + q4 * 24;
        float h[24];
        #pragma unroll
        for (int j = 0; j < 6; ++j) {
            fx4 v = *reinterpret_cast<const fx4*>(row + 4 * j);
            h[4*j]=v.x; h[4*j+1]=v.y; h[4*j+2]=v.z; h[4*j+3]=v.w;
        }
        float s = 0.f, s2 = 0.f;
        #pragma unroll
        for (int j = 0; j < 24; ++j) { s += h[j]; s2 = fmaf(h[j], h[j], s2); }
        s  += __shfl_xor(s, 1);  s  += __shfl_xor(s, 2);
        s2 += __shfl_xor(s2, 1); s2 += __shfl_xor(s2, 2);
        const float mu = s * (1.f/CC);
        const float rs = rsqrtf(s2 * (1.f/CC) - mu * mu + LEPS);
        unsigned short t[24];
        #pragma unroll
        for (int j = 0; j < 24; ++j) {
            int c = q4 * 24 + j;
            t[j] = f2bf((h[j] - mu) * rs * g2[c] + b2[c]);
        }
        #pragma unroll
        for (int j = 0; j < 6; ++j) {
            ull_t pk = (ull_t)t[4*j] | ((ull_t)t[4*j+1] << 16) |
                       ((ull_t)t[4*j+2] << 32) | ((ull_t)t[4*j+3] << 48);
            *reinterpret_cast<ull_t*>(&Hn[tl * LDH + q4 * 24 + 4*j]) = pk;
        }
    }
    __syncthreads();

    fx4 oacc[6];
    #pragma unroll
    for (int nt = 0; nt < 6; ++nt) oacc[nt] = (fx4){0.f,0.f,0.f,0.f};

    for (int ck = 0; ck < 6; ++ck) {
        // fc1: A from Hn (LDS), B direct from w1t (global)
        fx4 a1[4];
        #pragma unroll
        for (int nt = 0; nt < 4; ++nt) a1[nt] = (fx4){0.f,0.f,0.f,0.f};
        #pragma unroll
        for (int ks = 0; ks < 3; ++ks) {
            s8v a = *reinterpret_cast<const s8v*>(&Hn[(wave*16 + l15)*LDH + ks*32 + g4*8]);
            #pragma unroll
            for (int nt = 0; nt < 4; ++nt) {
                s8v b = *reinterpret_cast<const s8v*>(
                    &w1t[(size_t)(ck*64 + nt*16 + l15) * 96 + ks*32 + g4*8]);
                a1[nt] = MFMA16(a, b, a1[nt]);
            }
        }
        __syncthreads();   // previous ck's Ac reads complete
        #pragma unroll
        for (int nt = 0; nt < 4; ++nt) {
            const float bb = bf1[ck * 64 + nt * 16 + l15];
            #pragma unroll
            for (int r = 0; r < 4; ++r) {
                float v0 = a1[nt][r] + bb;
                Ac[(wave*16 + g4*4 + r) * LDA + nt*16 + l15] = f2bf(gelu_t(gelu_t(v0)));
            }
        }
        __syncthreads();
        // fc2: A from Ac (LDS), B direct from w2t (global)
        #pragma unroll
        for (int ks = 0; ks < 2; ++ks) {
            s8v a = *reinterpret_cast<const s8v*>(&Ac[(wave*16 + l15)*LDA + ks*32 + g4*8]);
            #pragma unroll
            for (int nt = 0; nt < 6; ++nt) {
                s8v b = *reinterpret_cast<const s8v*>(
                    &w2t[(size_t)(nt*16 + l15) * 384 + ck*64 + ks*32 + g4*8]);
                oacc[nt] = MFMA16(a, b, oacc[nt]);
            }
        }
    }

    const int rowb = blk * 64 + wave * 16 + g4 * 4;
    #pragma unroll
    for (int nt = 0; nt < 6; ++nt) {
        const int col = nt * 16 + l15;
        const float bb = bf2[col];
        #pragma unroll
        for (int r = 0; r < 4; ++r) {
            const size_t idx = (size_t)(rowb + r) * CC + col;
            xio[idx] = xio[idx] + oacc[nt][r] + bb;
        }
    }
}

extern "C" void kernel_launch(void* const* d_in, const int* in_sizes, int n_in,
                              void* d_out, int out_size, void* d_ws, size_t ws_size,
                              hipStream_t stream)
{
    const float* x    = (const float*)d_in[0];
    const float* n1g  = (const float*)d_in[1];
    const float* n1b  = (const float*)d_in[2];
    const float* qw   = (const float*)d_in[3];
    const float* qb   = (const float*)d_in[4];
    const float* btab = (const float*)d_in[5];
    const float* pw   = (const float*)d_in[6];
    const float* pb   = (const float*)d_in[7];
    const float* n2g  = (const float*)d_in[8];
    const float* n2b  = (const float*)d_in[9];
    const float* w1   = (const float*)d_in[10];
    const float* bf1  = (const float*)d_in[11];
    const float* w2   = (const float*)d_in[12];
    const float* bf2  = (const float*)d_in[13];
    float* out = (float*)d_out;

    float* qkv = (float*)d_ws;                                    // TOT*288 fp32
    unsigned short* wbf = (unsigned short*)((char*)d_ws + (size_t)TOT * 288 * 4);
    unsigned short* qwt = wbf;
    unsigned short* pwt = qwt + 288 * 96;
    unsigned short* w1t = pwt + 96 * 96;
    unsigned short* w2t = w1t + 384 * 96;
    float* bmt = (float*)(wbf + 110592);                          // [4][3][49][64]

    p0_prep <<<579, 256, 0, stream>>>(qw, pw, w1, w2, btab, wbf);
    k1_qkv  <<<TOT/64, 256, 0, stream>>>(x, n1g, n1b, qwt, qb, qkv);
    k2_attn <<<BB*NWIN*NHD, 64, 0, stream>>>(qkv, bmt);
    k2b_proj<<<TOT/64, 256, 0, stream>>>(qkv, pwt, pb, x, out);
    k3_mlp  <<<TOT/64, 256, 0, stream>>>(out, n2g, n2b, w1t, bf1, w2t, bf2);
}

// Round 8
// 168.221 us; speedup vs baseline: 1.3390x; 1.3390x over previous
//
#include <hip/hip_runtime.h>
#include <math.h>

#define BB   32
#define HH   56
#define WWI  56
#define CC   96
#define NHD  3
#define WSZ  7
#define SHF  3
#define NTK  49
#define NWIN 64
#define HDM  32
#define TOT  (BB*HH*WWI)               // 100352
#define QKSCALE 0.17677669529663687f
#define LEPS 1e-3f

typedef __attribute__((ext_vector_type(8))) short s8v;   // 8 bf16 (4 VGPRs)
typedef __attribute__((ext_vector_type(4))) float fx4;   // 4 fp32
typedef unsigned long long ull_t;

#define MFMA16(a,b,c) __builtin_amdgcn_mfma_f32_16x16x32_bf16((a),(b),(c),0,0,0)

__device__ __forceinline__ unsigned short f2bf(float f) {
    union { float f; unsigned u; } v; v.f = f;
    unsigned r = v.u + 0x7FFFu + ((v.u >> 16) & 1u);
    return (unsigned short)(r >> 16);
}

// sigmoid-form gelu (tanh approx): |err vs exact| <~2e-3, ~8 VALU ops vs ~28 for erff
__device__ __forceinline__ float gelu_t(float x) {
    float x3 = x * x * x;
    float z = -1.5957691216f * fmaf(0.044715f, x3, x);
    return x * __builtin_amdgcn_rcpf(1.f + __expf(z));
}

// windowed token id -> original flat token id (roll(-3,-3) + window partition)
__device__ __forceinline__ int wtok_to_orig(int wt) {
    int win = wt / NTK;
    int p   = wt - win * NTK;
    int b   = win >> 6;
    int w   = win & 63;
    int wi = w >> 3, wj = w & 7;
    int pi = p / WSZ, pj = p - pi * WSZ;
    int r = wi * WSZ + pi + SHF; if (r >= HH) r -= HH;
    int c = wj * WSZ + pj + SHF; if (c >= WWI) c -= WWI;
    return b * (HH * WWI) + r * WWI + c;
}

// ---------- P0: weight transpose/bf16 + combined bias+mask table ----------
extern "C" __global__ void p0_prep(const float* __restrict__ qw, const float* __restrict__ pw,
                                   const float* __restrict__ w1, const float* __restrict__ w2,
                                   const float* __restrict__ btab,
                                   unsigned short* __restrict__ wsw)
{
    int i = blockIdx.x * 256 + threadIdx.x;
    if (i < 27648) {                       // qwt[288][96]
        int n = i / 96, k = i - n * 96;
        wsw[i] = f2bf(qw[k * 288 + n]);
    } else if (i < 36864) {                // pwt[96][96]
        int j = i - 27648; int n = j / 96, k = j - n * 96;
        wsw[i] = f2bf(pw[k * 96 + n]);
    } else if (i < 73728) {                // w1t[384][96]
        int j = i - 36864; int n = j / 96, k = j - n * 96;
        wsw[i] = f2bf(w1[k * 384 + n]);
    } else if (i < 110592) {               // w2t[96][384]
        int j = i - 73728; int n = j / 384, k = j - n * 384;
        wsw[i] = f2bf(w2[k * 96 + n]);
    } else if (i < 148224) {               // BM table (fp32)
        float* bm = (float*)(wsw + 110592);
        int j = i - 110592;
        int n = j & 63, mh = j >> 6;
        int m = mh % 49, t = mh / 49;
        int hd = t % 3, cls = t / 3;       // cls = (wi==7)*2 + (wj==7)
        float val = 0.f;
        if (n < 49) {
            int it = m / 7, jt = m - it * 7;
            int iu = n / 7, ju = n - iu * 7;
            int li  = (cls & 2) ? (it < 4 ? 1 : 2) : 0;
            int lj  = (cls & 1) ? (jt < 4 ? 1 : 2) : 0;
            int lui = (cls & 2) ? (iu < 4 ? 1 : 2) : 0;
            int luj = (cls & 1) ? (ju < 4 ? 1 : 2) : 0;
            int bidx = (jt - ju + 6) * 13 + (it - iu + 6);
            val = btab[bidx * 3 + hd] + ((li*3+lj) == (lui*3+luj) ? 0.f : -100.f);
        }
        bm[j] = val;
    }
}

// ---------- K1: gather + LN1 + QKV MFMA GEMM (R6 LDS-staged form) ----------
#define LDH 104
extern "C" __global__ void __launch_bounds__(256, 4) k1_qkv(
    const float* __restrict__ x, const float* __restrict__ g1, const float* __restrict__ b1,
    const unsigned short* __restrict__ qwt, const float* __restrict__ qb,
    float* __restrict__ qkv)
{
    __shared__ unsigned short Hn[64 * LDH];
    __shared__ unsigned short Wc[96 * LDH];
    const int tid = threadIdx.x, wave = tid >> 6, lane = tid & 63;
    const int blk = blockIdx.x;

    { // LN1: 4 lanes per token
        const int tl = tid >> 2, q4 = tid & 3;
        const int orig = wtok_to_orig(blk * 64 + tl);
        const float* row = x + (size_t)orig * CC + q4 * 24;
        float h[24];
        #pragma unroll
        for (int j = 0; j < 6; ++j) {
            fx4 v = *reinterpret_cast<const fx4*>(row + 4 * j);
            h[4*j]=v.x; h[4*j+1]=v.y; h[4*j+2]=v.z; h[4*j+3]=v.w;
        }
        float s = 0.f, s2 = 0.f;
        #pragma unroll
        for (int j = 0; j < 24; ++j) { s += h[j]; s2 = fmaf(h[j], h[j], s2); }
        s  += __shfl_xor(s, 1);  s  += __shfl_xor(s, 2);
        s2 += __shfl_xor(s2, 1); s2 += __shfl_xor(s2, 2);
        const float mu = s * (1.f/CC);
        const float rs = rsqrtf(s2 * (1.f/CC) - mu * mu + LEPS);
        unsigned short t[24];
        #pragma unroll
        for (int j = 0; j < 24; ++j) {
            int c = q4 * 24 + j;
            t[j] = f2bf((h[j] - mu) * rs * g1[c] + b1[c]);
        }
        #pragma unroll
        for (int j = 0; j < 6; ++j) {
            ull_t pk = (ull_t)t[4*j] | ((ull_t)t[4*j+1] << 16) |
                       ((ull_t)t[4*j+2] << 32) | ((ull_t)t[4*j+3] << 48);
            *reinterpret_cast<ull_t*>(&Hn[tl * LDH + q4 * 24 + 4*j]) = pk;
        }
    }

    for (int ck = 0; ck < 3; ++ck) {
        for (int i = tid; i < 96 * 12; i += 256) {
            int r = i / 12, k0 = (i - r * 12) * 8;
            *reinterpret_cast<s8v*>(&Wc[r * LDH + k0]) =
                *reinterpret_cast<const s8v*>(&qwt[(ck * 96 + r) * 96 + k0]);
        }
        __syncthreads();
        fx4 acc[6];
        #pragma unroll
        for (int nt = 0; nt < 6; ++nt) acc[nt] = (fx4){0.f,0.f,0.f,0.f};
        #pragma unroll
        for (int ks = 0; ks < 3; ++ks) {
            s8v a = *reinterpret_cast<const s8v*>(&Hn[(wave*16 + (lane&15))*LDH + ks*32 + (lane>>4)*8]);
            #pragma unroll
            for (int nt = 0; nt < 6; ++nt) {
                s8v b = *reinterpret_cast<const s8v*>(&Wc[(nt*16 + (lane&15))*LDH + ks*32 + (lane>>4)*8]);
                acc[nt] = MFMA16(a, b, acc[nt]);
            }
        }
        const int rowb = blk * 64 + wave * 16 + ((lane>>4)) * 4;
        #pragma unroll
        for (int nt = 0; nt < 6; ++nt) {
            const int col = ck * 96 + nt * 16 + (lane & 15);
            const float qbc = qb[col];
            #pragma unroll
            for (int r = 0; r < 4; ++r)
                qkv[(size_t)(rowb + r) * 288 + col] = acc[nt][r] + qbc;
        }
        __syncthreads();
    }
}

// ---------- K2: MFMA attention, 1 wave = 1 (window, head) ----------
extern "C" __global__ void __launch_bounds__(64, 2) k2_attn(
    float* __restrict__ qkv, const float* __restrict__ bm)
{
    __shared__ unsigned short P[64][72];   // 9216 B
    const int lane = threadIdx.x;
    const int l15 = lane & 15, g4 = lane >> 4;
    const int task = blockIdx.x;
    const int win = task / 3, h = task - win * 3;
    const int g0  = win * NTK;
    const int w   = win & 63;
    const int cls = (((w >> 3) == 7) ? 2 : 0) + (((w & 7) == 7) ? 1 : 0);
    const float* BMh = bm + ((size_t)(cls * 3 + h)) * 49 * 64;

    s8v aq[4], bk[4];
    #pragma unroll
    for (int mt = 0; mt < 4; ++mt) {
        int tok = mt * 16 + l15; if (tok > 48) tok = 48;
        const float* qp = &qkv[(size_t)(g0 + tok) * 288 + h * HDM + g4 * 8];
        fx4 v0 = *reinterpret_cast<const fx4*>(qp);
        fx4 v1 = *reinterpret_cast<const fx4*>(qp + 4);
        union { s8v v; unsigned short u[8]; } pa;
        pa.u[0]=f2bf(v0.x*QKSCALE); pa.u[1]=f2bf(v0.y*QKSCALE);
        pa.u[2]=f2bf(v0.z*QKSCALE); pa.u[3]=f2bf(v0.w*QKSCALE);
        pa.u[4]=f2bf(v1.x*QKSCALE); pa.u[5]=f2bf(v1.y*QKSCALE);
        pa.u[6]=f2bf(v1.z*QKSCALE); pa.u[7]=f2bf(v1.w*QKSCALE);
        aq[mt] = pa.v;
        const float* kp = &qkv[(size_t)(g0 + tok) * 288 + 96 + h * HDM + g4 * 8];
        fx4 k0 = *reinterpret_cast<const fx4*>(kp);
        fx4 k1 = *reinterpret_cast<const fx4*>(kp + 4);
        union { s8v v; unsigned short u[8]; } pb;
        pb.u[0]=f2bf(k0.x); pb.u[1]=f2bf(k0.y); pb.u[2]=f2bf(k0.z); pb.u[3]=f2bf(k0.w);
        pb.u[4]=f2bf(k1.x); pb.u[5]=f2bf(k1.y); pb.u[6]=f2bf(k1.z); pb.u[7]=f2bf(k1.w);
        bk[mt] = pb.v;
    }

    fx4 sc[4][4];
    #pragma unroll
    for (int mt = 0; mt < 4; ++mt)
        #pragma unroll
        for (int nt = 0; nt < 4; ++nt)
            sc[mt][nt] = MFMA16(aq[mt], bk[nt], ((fx4){0.f,0.f,0.f,0.f}));

    #pragma unroll
    for (int mt = 0; mt < 4; ++mt) {
        #pragma unroll
        for (int r = 0; r < 4; ++r) {
            const int m = mt * 16 + g4 * 4 + r;
            const int mc = m > 48 ? 48 : m;
            float rs1 = 0.f;
            #pragma unroll
            for (int nt = 0; nt < 4; ++nt) {
                const int n = nt * 16 + l15;
                float s = sc[mt][nt][r] + BMh[mc * 64 + n];
                float e = (n < NTK) ? __expf(s) : 0.f;
                sc[mt][nt][r] = e;
                rs1 += e;
            }
            rs1 += __shfl_xor(rs1, 1); rs1 += __shfl_xor(rs1, 2);
            rs1 += __shfl_xor(rs1, 4); rs1 += __shfl_xor(rs1, 8);
            const float iv1 = 1.f / rs1;
            float rs2 = 0.f;
            #pragma unroll
            for (int nt = 0; nt < 4; ++nt) {
                const int n = nt * 16 + l15;
                float e2 = (n < NTK) ? __expf(sc[mt][nt][r] * iv1) : 0.f;
                sc[mt][nt][r] = e2;
                rs2 += e2;
            }
            rs2 += __shfl_xor(rs2, 1); rs2 += __shfl_xor(rs2, 2);
            rs2 += __shfl_xor(rs2, 4); rs2 += __shfl_xor(rs2, 8);
            const float iv2 = 1.f / rs2;
            #pragma unroll
            for (int nt = 0; nt < 4; ++nt)
                P[m][nt * 16 + l15] = f2bf(sc[mt][nt][r] * iv2);
        }
    }
    __syncthreads();

    fx4 oc[4][2];
    #pragma unroll
    for (int mt = 0; mt < 4; ++mt) { oc[mt][0] = (fx4){0.f,0.f,0.f,0.f}; oc[mt][1] = (fx4){0.f,0.f,0.f,0.f}; }
    #pragma unroll
    for (int ks = 0; ks < 2; ++ks) {
        s8v vb[2];
        #pragma unroll
        for (int nt = 0; nt < 2; ++nt) {
            union { s8v v; unsigned short u[8]; } pv;
            #pragma unroll
            for (int j = 0; j < 8; ++j) {
                int tok = ks * 32 + g4 * 8 + j; if (tok > 48) tok = 48;
                pv.u[j] = f2bf(qkv[(size_t)(g0 + tok) * 288 + 192 + h * HDM + nt * 16 + l15]);
            }
            vb[nt] = pv.v;
        }
        #pragma unroll
        for (int mt = 0; mt < 4; ++mt) {
            s8v pa = *reinterpret_cast<const s8v*>(&P[mt * 16 + l15][ks * 32 + g4 * 8]);
            oc[mt][0] = MFMA16(pa, vb[0], oc[mt][0]);
            oc[mt][1] = MFMA16(pa, vb[1], oc[mt][1]);
        }
    }
    #pragma unroll
    for (int mt = 0; mt < 4; ++mt) {
        #pragma unroll
        for (int r = 0; r < 4; ++r) {
            const int m = mt * 16 + g4 * 4 + r;
            if (m < NTK) {
                qkv[(size_t)(g0 + m) * 288 + h * HDM + l15]      = oc[mt][0][r];
                qkv[(size_t)(g0 + m) * 288 + h * HDM + 16 + l15] = oc[mt][1][r];
            }
        }
    }
}

// ---------- K2b: proj MFMA GEMM + residual + un-shift scatter (R6 form) ----------
extern "C" __global__ void __launch_bounds__(256, 4) k2b_proj(
    const float* __restrict__ qkv, const unsigned short* __restrict__ pwt,
    const float* __restrict__ pb, const float* __restrict__ x, float* __restrict__ out)
{
    __shared__ unsigned short Ao[64 * LDH];
    __shared__ unsigned short Wc[96 * LDH];
    const int tid = threadIdx.x, wave = tid >> 6, lane = tid & 63;
    const int blk = blockIdx.x;

    {
        const int tl = tid >> 2, q4 = tid & 3;
        const float* row = qkv + (size_t)(blk * 64 + tl) * 288 + q4 * 24;
        unsigned short t[24];
        #pragma unroll
        for (int j = 0; j < 6; ++j) {
            fx4 v = *reinterpret_cast<const fx4*>(row + 4 * j);
            t[4*j]=f2bf(v.x); t[4*j+1]=f2bf(v.y); t[4*j+2]=f2bf(v.z); t[4*j+3]=f2bf(v.w);
        }
        #pragma unroll
        for (int j = 0; j < 6; ++j) {
            ull_t pk = (ull_t)t[4*j] | ((ull_t)t[4*j+1] << 16) |
                       ((ull_t)t[4*j+2] << 32) | ((ull_t)t[4*j+3] << 48);
            *reinterpret_cast<ull_t*>(&Ao[tl * LDH + q4 * 24 + 4*j]) = pk;
        }
    }
    for (int i = tid; i < 96 * 12; i += 256) {
        int r = i / 12, k0 = (i - r * 12) * 8;
        *reinterpret_cast<s8v*>(&Wc[r * LDH + k0]) =
            *reinterpret_cast<const s8v*>(&pwt[r * 96 + k0]);
    }
    __syncthreads();

    fx4 acc[6];
    #pragma unroll
    for (int nt = 0; nt < 6; ++nt) acc[nt] = (fx4){0.f,0.f,0.f,0.f};
    #pragma unroll
    for (int ks = 0; ks < 3; ++ks) {
        s8v a = *reinterpret_cast<const s8v*>(&Ao[(wave*16 + (lane&15))*LDH + ks*32 + (lane>>4)*8]);
        #pragma unroll
        for (int nt = 0; nt < 6; ++nt) {
            s8v b = *reinterpret_cast<const s8v*>(&Wc[(nt*16 + (lane&15))*LDH + ks*32 + (lane>>4)*8]);
            acc[nt] = MFMA16(a, b, acc[nt]);
        }
    }
    int orig[4];
    #pragma unroll
    for (int r = 0; r < 4; ++r)
        orig[r] = wtok_to_orig(blk * 64 + wave * 16 + ((lane>>4)) * 4 + r);
    #pragma unroll
    for (int nt = 0; nt < 6; ++nt) {
        const int col = nt * 16 + (lane & 15);
        const float pbc = pb[col];
        #pragma unroll
        for (int r = 0; r < 4; ++r) {
            const size_t idx = (size_t)orig[r] * CC + col;
            out[idx] = acc[nt][r] + pbc + x[idx];
        }
    }
}

// ---------- K3: LN2 + fc1 + gelu_t^2 + fc2 + residual ----------
// R6 LDS-staged structure + gelu_t + 128 tokens/block (halves per-token
// staging traffic and barriers). LDS 72.2 KB -> 2 blocks/CU.
#define LDA 72
extern "C" __global__ void __launch_bounds__(256, 2) k3_mlp(
    float* __restrict__ xio, const float* __restrict__ g2, const float* __restrict__ b2,
    const unsigned short* __restrict__ w1t, const float* __restrict__ bf1,
    const unsigned short* __restrict__ w2t, const float* __restrict__ bf2)
{
    __shared__ unsigned short Hn[128 * LDH];   // 26624 B
    __shared__ unsigned short W1c[64 * LDH];   // 13312 B
    __shared__ unsigned short Ac[128 * LDA];   // 18432 B
    __shared__ unsigned short W2c[96 * LDA];   // 13824 B  (total 72192)
    const int tid = threadIdx.x, wave = tid >> 6, lane = tid & 63;
    const int l15 = lane & 15, g4 = lane >> 4;
    const int blk = blockIdx.x;

    // LN2: two passes of 64 tokens, 4 lanes/token
    #pragma unroll 1
    for (int p = 0; p < 2; ++p) {
        const int tl = tid >> 2, q4 = tid & 3;
        const float* row = xio + (size_t)(blk * 128 + p * 64 + tl) * CC + q4 * 24;
        float h[24];
        #pragma unroll
        for (int j = 0; j < 6; ++j) {
            fx4 v = *reinterpret_cast<const fx4*>(row + 4 * j);
            h[4*j]=v.x; h[4*j+1]=v.y; h[4*j+2]=v.z; h[4*j+3]=v.w;
        }
        float s = 0.f, s2 = 0.f;
        #pragma unroll
        for (int j = 0; j < 24; ++j) { s += h[j]; s2 = fmaf(h[j], h[j], s2); }
        s  += __shfl_xor(s, 1);  s  += __shfl_xor(s, 2);
        s2 += __shfl_xor(s2, 1); s2 += __shfl_xor(s2, 2);
        const float mu = s * (1.f/CC);
        const float rs = rsqrtf(s2 * (1.f/CC) - mu * mu + LEPS);
        unsigned short t[24];
        #pragma unroll
        for (int j = 0; j < 24; ++j) {
            int c = q4 * 24 + j;
            t[j] = f2bf((h[j] - mu) * rs * g2[c] + b2[c]);
        }
        #pragma unroll
        for (int j = 0; j < 6; ++j) {
            ull_t pk = (ull_t)t[4*j] | ((ull_t)t[4*j+1] << 16) |
                       ((ull_t)t[4*j+2] << 32) | ((ull_t)t[4*j+3] << 48);
            *reinterpret_cast<ull_t*>(&Hn[(p * 64 + tl) * LDH + q4 * 24 + 4*j]) = pk;
        }
    }

    fx4 oacc[2][6];
    #pragma unroll
    for (int sub = 0; sub < 2; ++sub)
        #pragma unroll
        for (int nt = 0; nt < 6; ++nt) oacc[sub][nt] = (fx4){0.f,0.f,0.f,0.f};

    for (int ck = 0; ck < 6; ++ck) {
        for (int i = tid; i < 64 * 12; i += 256) {       // W1 chunk [64 n][96 k]
            int r = i / 12, k0 = (i - r * 12) * 8;
            *reinterpret_cast<s8v*>(&W1c[r * LDH + k0]) =
                *reinterpret_cast<const s8v*>(&w1t[(ck * 64 + r) * 96 + k0]);
        }
        for (int i = tid; i < 96 * 8; i += 256) {        // W2 chunk [96 n][64 k]
            int r = i / 8, k0 = (i - r * 8) * 8;
            *reinterpret_cast<s8v*>(&W2c[r * LDA + k0]) =
                *reinterpret_cast<const s8v*>(&w2t[r * 384 + ck * 64 + k0]);
        }
        __syncthreads();

        fx4 a1[2][4];
        #pragma unroll
        for (int sub = 0; sub < 2; ++sub)
            #pragma unroll
            for (int nt = 0; nt < 4; ++nt) a1[sub][nt] = (fx4){0.f,0.f,0.f,0.f};
        #pragma unroll
        for (int sub = 0; sub < 2; ++sub) {
            #pragma unroll
            for (int ks = 0; ks < 3; ++ks) {
                s8v a = *reinterpret_cast<const s8v*>(
                    &Hn[(wave*32 + sub*16 + l15)*LDH + ks*32 + g4*8]);
                #pragma unroll
                for (int nt = 0; nt < 4; ++nt) {
                    s8v b = *reinterpret_cast<const s8v*>(&W1c[(nt*16 + l15)*LDH + ks*32 + g4*8]);
                    a1[sub][nt] = MFMA16(a, b, a1[sub][nt]);
                }
            }
        }
        #pragma unroll
        for (int sub = 0; sub < 2; ++sub) {
            #pragma unroll
            for (int nt = 0; nt < 4; ++nt) {
                const float bb = bf1[ck * 64 + nt * 16 + l15];
                #pragma unroll
                for (int r = 0; r < 4; ++r) {
                    float v0 = a1[sub][nt][r] + bb;
                    Ac[(wave*32 + sub*16 + g4*4 + r) * LDA + nt*16 + l15] =
                        f2bf(gelu_t(gelu_t(v0)));
                }
            }
        }
        __syncthreads();

        #pragma unroll
        for (int sub = 0; sub < 2; ++sub) {
            #pragma unroll
            for (int ks = 0; ks < 2; ++ks) {
                s8v a = *reinterpret_cast<const s8v*>(
                    &Ac[(wave*32 + sub*16 + l15)*LDA + ks*32 + g4*8]);
                #pragma unroll
                for (int nt = 0; nt < 6; ++nt) {
                    s8v b = *reinterpret_cast<const s8v*>(&W2c[(nt*16 + l15)*LDA + ks*32 + g4*8]);
                    oacc[sub][nt] = MFMA16(a, b, oacc[sub][nt]);
                }
            }
        }
        __syncthreads();
    }

    #pragma unroll
    for (int sub = 0; sub < 2; ++sub) {
        const int rowb = blk * 128 + wave * 32 + sub * 16 + g4 * 4;
        #pragma unroll
        for (int nt = 0; nt < 6; ++nt) {
            const int col = nt * 16 + l15;
            const float bb = bf2[col];
            #pragma unroll
            for (int r = 0; r < 4; ++r) {
                const size_t idx = (size_t)(rowb + r) * CC + col;
                xio[idx] = xio[idx] + oacc[sub][nt][r] + bb;
            }
        }
    }
}

extern "C" void kernel_launch(void* const* d_in, const int* in_sizes, int n_in,
                              void* d_out, int out_size, void* d_ws, size_t ws_size,
                              hipStream_t stream)
{
    const float* x    = (const float*)d_in[0];
    const float* n1g  = (const float*)d_in[1];
    const float* n1b  = (const float*)d_in[2];
    const float* qw   = (const float*)d_in[3];
    const float* qb   = (const float*)d_in[4];
    const float* btab = (const float*)d_in[5];
    const float* pw   = (const float*)d_in[6];
    const float* pb   = (const float*)d_in[7];
    const float* n2g  = (const float*)d_in[8];
    const float* n2b  = (const float*)d_in[9];
    const float* w1   = (const float*)d_in[10];
    const float* bf1  = (const float*)d_in[11];
    const float* w2   = (const float*)d_in[12];
    const float* bf2  = (const float*)d_in[13];
    float* out = (float*)d_out;

    float* qkv = (float*)d_ws;                                    // TOT*288 fp32
    unsigned short* wbf = (unsigned short*)((char*)d_ws + (size_t)TOT * 288 * 4);
    unsigned short* qwt = wbf;
    unsigned short* pwt = qwt + 288 * 96;
    unsigned short* w1t = pwt + 96 * 96;
    unsigned short* w2t = w1t + 384 * 96;
    float* bmt = (float*)(wbf + 110592);                          // [4][3][49][64]

    p0_prep <<<579, 256, 0, stream>>>(qw, pw, w1, w2, btab, wbf);
    k1_qkv  <<<TOT/64, 256, 0, stream>>>(x, n1g, n1b, qwt, qb, qkv);
    k2_attn <<<BB*NWIN*NHD, 64, 0, stream>>>(qkv, bmt);
    k2b_proj<<<TOT/64, 256, 0, stream>>>(qkv, pwt, pb, x, out);
    k3_mlp  <<<TOT/128, 256, 0, stream>>>(out, n2g, n2b, w1t, bf1, w2t, bf2);
}

// Round 9
// 164.080 us; speedup vs baseline: 1.3728x; 1.0252x over previous
//
#include <hip/hip_runtime.h>
#include <math.h>

#define BB   32
#define HH   56
#define WWI  56
#define CC   96
#define NHD  3
#define WSZ  7
#define SHF  3
#define NTK  49
#define NWIN 64
#define HDM  32
#define TOT  (BB*HH*WWI)               // 100352
#define QKSCALE 0.17677669529663687f
#define LEPS 1e-3f

typedef __attribute__((ext_vector_type(8))) short s8v;   // 8 bf16 (4 VGPRs)
typedef __attribute__((ext_vector_type(4))) float fx4;   // 4 fp32
typedef unsigned long long ull_t;

#define MFMA16(a,b,c) __builtin_amdgcn_mfma_f32_16x16x32_bf16((a),(b),(c),0,0,0)

__device__ __forceinline__ unsigned short f2bf(float f) {
    union { float f; unsigned u; } v; v.f = f;
    unsigned r = v.u + 0x7FFFu + ((v.u >> 16) & 1u);
    return (unsigned short)(r >> 16);
}

// sigmoid-form gelu (tanh approx): |err vs exact| <~2e-3, ~8 VALU ops vs ~28 for erff
__device__ __forceinline__ float gelu_t(float x) {
    float x3 = x * x * x;
    float z = -1.5957691216f * fmaf(0.044715f, x3, x);
    return x * __builtin_amdgcn_rcpf(1.f + __expf(z));
}

// windowed token id -> original flat token id (roll(-3,-3) + window partition)
__device__ __forceinline__ int wtok_to_orig(int wt) {
    int win = wt / NTK;
    int p   = wt - win * NTK;
    int b   = win >> 6;
    int w   = win & 63;
    int wi = w >> 3, wj = w & 7;
    int pi = p / WSZ, pj = p - pi * WSZ;
    int r = wi * WSZ + pi + SHF; if (r >= HH) r -= HH;
    int c = wj * WSZ + pj + SHF; if (c >= WWI) c -= WWI;
    return b * (HH * WWI) + r * WWI + c;
}

// ---------- P0: weight transpose/bf16 + combined bias+mask table ----------
extern "C" __global__ void p0_prep(const float* __restrict__ qw, const float* __restrict__ pw,
                                   const float* __restrict__ w1, const float* __restrict__ w2,
                                   const float* __restrict__ btab,
                                   unsigned short* __restrict__ wsw)
{
    int i = blockIdx.x * 256 + threadIdx.x;
    if (i < 27648) {                       // qwt[288][96]
        int n = i / 96, k = i - n * 96;
        wsw[i] = f2bf(qw[k * 288 + n]);
    } else if (i < 36864) {                // pwt[96][96]
        int j = i - 27648; int n = j / 96, k = j - n * 96;
        wsw[i] = f2bf(pw[k * 96 + n]);
    } else if (i < 73728) {                // w1t[384][96]
        int j = i - 36864; int n = j / 96, k = j - n * 96;
        wsw[i] = f2bf(w1[k * 384 + n]);
    } else if (i < 110592) {               // w2t[96][384]
        int j = i - 73728; int n = j / 384, k = j - n * 384;
        wsw[i] = f2bf(w2[k * 96 + n]);
    } else if (i < 148224) {               // BM table (fp32)
        float* bm = (float*)(wsw + 110592);
        int j = i - 110592;
        int n = j & 63, mh = j >> 6;
        int m = mh % 49, t = mh / 49;
        int hd = t % 3, cls = t / 3;       // cls = (wi==7)*2 + (wj==7)
        float val = 0.f;
        if (n < 49) {
            int it = m / 7, jt = m - it * 7;
            int iu = n / 7, ju = n - iu * 7;
            int li  = (cls & 2) ? (it < 4 ? 1 : 2) : 0;
            int lj  = (cls & 1) ? (jt < 4 ? 1 : 2) : 0;
            int lui = (cls & 2) ? (iu < 4 ? 1 : 2) : 0;
            int luj = (cls & 1) ? (ju < 4 ? 1 : 2) : 0;
            int bidx = (jt - ju + 6) * 13 + (it - iu + 6);
            val = btab[bidx * 3 + hd] + ((li*3+lj) == (lui*3+luj) ? 0.f : -100.f);
        }
        bm[j] = val;
    }
}

// ---------- K1: gather + LN1 + QKV MFMA GEMM (R6 LDS-staged form) ----------
#define LDH 104
extern "C" __global__ void __launch_bounds__(256, 4) k1_qkv(
    const float* __restrict__ x, const float* __restrict__ g1, const float* __restrict__ b1,
    const unsigned short* __restrict__ qwt, const float* __restrict__ qb,
    float* __restrict__ qkv)
{
    __shared__ unsigned short Hn[64 * LDH];
    __shared__ unsigned short Wc[96 * LDH];
    const int tid = threadIdx.x, wave = tid >> 6, lane = tid & 63;
    const int blk = blockIdx.x;

    { // LN1: 4 lanes per token
        const int tl = tid >> 2, q4 = tid & 3;
        const int orig = wtok_to_orig(blk * 64 + tl);
        const float* row = x + (size_t)orig * CC + q4 * 24;
        float h[24];
        #pragma unroll
        for (int j = 0; j < 6; ++j) {
            fx4 v = *reinterpret_cast<const fx4*>(row + 4 * j);
            h[4*j]=v.x; h[4*j+1]=v.y; h[4*j+2]=v.z; h[4*j+3]=v.w;
        }
        float s = 0.f, s2 = 0.f;
        #pragma unroll
        for (int j = 0; j < 24; ++j) { s += h[j]; s2 = fmaf(h[j], h[j], s2); }
        s  += __shfl_xor(s, 1);  s  += __shfl_xor(s, 2);
        s2 += __shfl_xor(s2, 1); s2 += __shfl_xor(s2, 2);
        const float mu = s * (1.f/CC);
        const float rs = rsqrtf(s2 * (1.f/CC) - mu * mu + LEPS);
        unsigned short t[24];
        #pragma unroll
        for (int j = 0; j < 24; ++j) {
            int c = q4 * 24 + j;
            t[j] = f2bf((h[j] - mu) * rs * g1[c] + b1[c]);
        }
        #pragma unroll
        for (int j = 0; j < 6; ++j) {
            ull_t pk = (ull_t)t[4*j] | ((ull_t)t[4*j+1] << 16) |
                       ((ull_t)t[4*j+2] << 32) | ((ull_t)t[4*j+3] << 48);
            *reinterpret_cast<ull_t*>(&Hn[tl * LDH + q4 * 24 + 4*j]) = pk;
        }
    }

    for (int ck = 0; ck < 3; ++ck) {
        for (int i = tid; i < 96 * 12; i += 256) {
            int r = i / 12, k0 = (i - r * 12) * 8;
            *reinterpret_cast<s8v*>(&Wc[r * LDH + k0]) =
                *reinterpret_cast<const s8v*>(&qwt[(ck * 96 + r) * 96 + k0]);
        }
        __syncthreads();
        fx4 acc[6];
        #pragma unroll
        for (int nt = 0; nt < 6; ++nt) acc[nt] = (fx4){0.f,0.f,0.f,0.f};
        #pragma unroll
        for (int ks = 0; ks < 3; ++ks) {
            s8v a = *reinterpret_cast<const s8v*>(&Hn[(wave*16 + (lane&15))*LDH + ks*32 + (lane>>4)*8]);
            #pragma unroll
            for (int nt = 0; nt < 6; ++nt) {
                s8v b = *reinterpret_cast<const s8v*>(&Wc[(nt*16 + (lane&15))*LDH + ks*32 + (lane>>4)*8]);
                acc[nt] = MFMA16(a, b, acc[nt]);
            }
        }
        const int rowb = blk * 64 + wave * 16 + ((lane>>4)) * 4;
        #pragma unroll
        for (int nt = 0; nt < 6; ++nt) {
            const int col = ck * 96 + nt * 16 + (lane & 15);
            const float qbc = qb[col];
            #pragma unroll
            for (int r = 0; r < 4; ++r)
                qkv[(size_t)(rowb + r) * 288 + col] = acc[nt][r] + qbc;
        }
        __syncthreads();
    }
}

// ---------- K2: MFMA attention, 1 wave = 1 (window, head) ----------
extern "C" __global__ void __launch_bounds__(64, 2) k2_attn(
    float* __restrict__ qkv, const float* __restrict__ bm)
{
    __shared__ unsigned short P[64][72];   // 9216 B
    const int lane = threadIdx.x;
    const int l15 = lane & 15, g4 = lane >> 4;
    const int task = blockIdx.x;
    const int win = task / 3, h = task - win * 3;
    const int g0  = win * NTK;
    const int w   = win & 63;
    const int cls = (((w >> 3) == 7) ? 2 : 0) + (((w & 7) == 7) ? 1 : 0);
    const float* BMh = bm + ((size_t)(cls * 3 + h)) * 49 * 64;

    s8v aq[4], bk[4];
    #pragma unroll
    for (int mt = 0; mt < 4; ++mt) {
        int tok = mt * 16 + l15; if (tok > 48) tok = 48;
        const float* qp = &qkv[(size_t)(g0 + tok) * 288 + h * HDM + g4 * 8];
        fx4 v0 = *reinterpret_cast<const fx4*>(qp);
        fx4 v1 = *reinterpret_cast<const fx4*>(qp + 4);
        union { s8v v; unsigned short u[8]; } pa;
        pa.u[0]=f2bf(v0.x*QKSCALE); pa.u[1]=f2bf(v0.y*QKSCALE);
        pa.u[2]=f2bf(v0.z*QKSCALE); pa.u[3]=f2bf(v0.w*QKSCALE);
        pa.u[4]=f2bf(v1.x*QKSCALE); pa.u[5]=f2bf(v1.y*QKSCALE);
        pa.u[6]=f2bf(v1.z*QKSCALE); pa.u[7]=f2bf(v1.w*QKSCALE);
        aq[mt] = pa.v;
        const float* kp = &qkv[(size_t)(g0 + tok) * 288 + 96 + h * HDM + g4 * 8];
        fx4 k0 = *reinterpret_cast<const fx4*>(kp);
        fx4 k1 = *reinterpret_cast<const fx4*>(kp + 4);
        union { s8v v; unsigned short u[8]; } pb;
        pb.u[0]=f2bf(k0.x); pb.u[1]=f2bf(k0.y); pb.u[2]=f2bf(k0.z); pb.u[3]=f2bf(k0.w);
        pb.u[4]=f2bf(k1.x); pb.u[5]=f2bf(k1.y); pb.u[6]=f2bf(k1.z); pb.u[7]=f2bf(k1.w);
        bk[mt] = pb.v;
    }

    fx4 sc[4][4];
    #pragma unroll
    for (int mt = 0; mt < 4; ++mt)
        #pragma unroll
        for (int nt = 0; nt < 4; ++nt)
            sc[mt][nt] = MFMA16(aq[mt], bk[nt], ((fx4){0.f,0.f,0.f,0.f}));

    #pragma unroll
    for (int mt = 0; mt < 4; ++mt) {
        #pragma unroll
        for (int r = 0; r < 4; ++r) {
            const int m = mt * 16 + g4 * 4 + r;
            const int mc = m > 48 ? 48 : m;
            float rs1 = 0.f;
            #pragma unroll
            for (int nt = 0; nt < 4; ++nt) {
                const int n = nt * 16 + l15;
                float s = sc[mt][nt][r] + BMh[mc * 64 + n];
                float e = (n < NTK) ? __expf(s) : 0.f;
                sc[mt][nt][r] = e;
                rs1 += e;
            }
            rs1 += __shfl_xor(rs1, 1); rs1 += __shfl_xor(rs1, 2);
            rs1 += __shfl_xor(rs1, 4); rs1 += __shfl_xor(rs1, 8);
            const float iv1 = 1.f / rs1;
            float rs2 = 0.f;
            #pragma unroll
            for (int nt = 0; nt < 4; ++nt) {
                const int n = nt * 16 + l15;
                float e2 = (n < NTK) ? __expf(sc[mt][nt][r] * iv1) : 0.f;
                sc[mt][nt][r] = e2;
                rs2 += e2;
            }
            rs2 += __shfl_xor(rs2, 1); rs2 += __shfl_xor(rs2, 2);
            rs2 += __shfl_xor(rs2, 4); rs2 += __shfl_xor(rs2, 8);
            const float iv2 = 1.f / rs2;
            #pragma unroll
            for (int nt = 0; nt < 4; ++nt)
                P[m][nt * 16 + l15] = f2bf(sc[mt][nt][r] * iv2);
        }
    }
    __syncthreads();

    fx4 oc[4][2];
    #pragma unroll
    for (int mt = 0; mt < 4; ++mt) { oc[mt][0] = (fx4){0.f,0.f,0.f,0.f}; oc[mt][1] = (fx4){0.f,0.f,0.f,0.f}; }
    #pragma unroll
    for (int ks = 0; ks < 2; ++ks) {
        s8v vb[2];
        #pragma unroll
        for (int nt = 0; nt < 2; ++nt) {
            union { s8v v; unsigned short u[8]; } pv;
            #pragma unroll
            for (int j = 0; j < 8; ++j) {
                int tok = ks * 32 + g4 * 8 + j; if (tok > 48) tok = 48;
                pv.u[j] = f2bf(qkv[(size_t)(g0 + tok) * 288 + 192 + h * HDM + nt * 16 + l15]);
            }
            vb[nt] = pv.v;
        }
        #pragma unroll
        for (int mt = 0; mt < 4; ++mt) {
            s8v pa = *reinterpret_cast<const s8v*>(&P[mt * 16 + l15][ks * 32 + g4 * 8]);
            oc[mt][0] = MFMA16(pa, vb[0], oc[mt][0]);
            oc[mt][1] = MFMA16(pa, vb[1], oc[mt][1]);
        }
    }
    #pragma unroll
    for (int mt = 0; mt < 4; ++mt) {
        #pragma unroll
        for (int r = 0; r < 4; ++r) {
            const int m = mt * 16 + g4 * 4 + r;
            if (m < NTK) {
                qkv[(size_t)(g0 + m) * 288 + h * HDM + l15]      = oc[mt][0][r];
                qkv[(size_t)(g0 + m) * 288 + h * HDM + 16 + l15] = oc[mt][1][r];
            }
        }
    }
}

// ---------- K2b: proj MFMA GEMM + residual + un-shift scatter (R6 form) ----------
extern "C" __global__ void __launch_bounds__(256, 4) k2b_proj(
    const float* __restrict__ qkv, const unsigned short* __restrict__ pwt,
    const float* __restrict__ pb, const float* __restrict__ x, float* __restrict__ out)
{
    __shared__ unsigned short Ao[64 * LDH];
    __shared__ unsigned short Wc[96 * LDH];
    const int tid = threadIdx.x, wave = tid >> 6, lane = tid & 63;
    const int blk = blockIdx.x;

    {
        const int tl = tid >> 2, q4 = tid & 3;
        const float* row = qkv + (size_t)(blk * 64 + tl) * 288 + q4 * 24;
        unsigned short t[24];
        #pragma unroll
        for (int j = 0; j < 6; ++j) {
            fx4 v = *reinterpret_cast<const fx4*>(row + 4 * j);
            t[4*j]=f2bf(v.x); t[4*j+1]=f2bf(v.y); t[4*j+2]=f2bf(v.z); t[4*j+3]=f2bf(v.w);
        }
        #pragma unroll
        for (int j = 0; j < 6; ++j) {
            ull_t pk = (ull_t)t[4*j] | ((ull_t)t[4*j+1] << 16) |
                       ((ull_t)t[4*j+2] << 32) | ((ull_t)t[4*j+3] << 48);
            *reinterpret_cast<ull_t*>(&Ao[tl * LDH + q4 * 24 + 4*j]) = pk;
        }
    }
    for (int i = tid; i < 96 * 12; i += 256) {
        int r = i / 12, k0 = (i - r * 12) * 8;
        *reinterpret_cast<s8v*>(&Wc[r * LDH + k0]) =
            *reinterpret_cast<const s8v*>(&pwt[r * 96 + k0]);
    }
    __syncthreads();

    fx4 acc[6];
    #pragma unroll
    for (int nt = 0; nt < 6; ++nt) acc[nt] = (fx4){0.f,0.f,0.f,0.f};
    #pragma unroll
    for (int ks = 0; ks < 3; ++ks) {
        s8v a = *reinterpret_cast<const s8v*>(&Ao[(wave*16 + (lane&15))*LDH + ks*32 + (lane>>4)*8]);
        #pragma unroll
        for (int nt = 0; nt < 6; ++nt) {
            s8v b = *reinterpret_cast<const s8v*>(&Wc[(nt*16 + (lane&15))*LDH + ks*32 + (lane>>4)*8]);
            acc[nt] = MFMA16(a, b, acc[nt]);
        }
    }
    int orig[4];
    #pragma unroll
    for (int r = 0; r < 4; ++r)
        orig[r] = wtok_to_orig(blk * 64 + wave * 16 + ((lane>>4)) * 4 + r);
    #pragma unroll
    for (int nt = 0; nt < 6; ++nt) {
        const int col = nt * 16 + (lane & 15);
        const float pbc = pb[col];
        #pragma unroll
        for (int r = 0; r < 4; ++r) {
            const size_t idx = (size_t)orig[r] * CC + col;
            out[idx] = acc[nt][r] + pbc + x[idx];
        }
    }
}

// ---------- K3: LN2 + fc1 + gelu_t^2 + fc2 + residual ----------
// 512 threads / 128 tokens: same 72.2 KB LDS (2 blocks/CU) but 8 waves/block
// -> 16 waves/CU (was 8). Each wave owns one 16-token sub-tile.
#define LDA 72
extern "C" __global__ void __launch_bounds__(512, 4) k3_mlp(
    float* __restrict__ xio, const float* __restrict__ g2, const float* __restrict__ b2,
    const unsigned short* __restrict__ w1t, const float* __restrict__ bf1,
    const unsigned short* __restrict__ w2t, const float* __restrict__ bf2)
{
    __shared__ unsigned short Hn[128 * LDH];   // 26624 B
    __shared__ unsigned short W1c[64 * LDH];   // 13312 B
    __shared__ unsigned short Ac[128 * LDA];   // 18432 B
    __shared__ unsigned short W2c[96 * LDA];   // 13824 B  (total 72192)
    const int tid = threadIdx.x, wave = tid >> 6, lane = tid & 63;
    const int l15 = lane & 15, g4 = lane >> 4;
    const int blk = blockIdx.x;

    { // LN2: 512 threads x 4 lanes/token = 128 tokens, one pass
        const int tl = tid >> 2, q4 = tid & 3;
        const float* row = xio + (size_t)(blk * 128 + tl) * CC + q4 * 24;
        float h[24];
        #pragma unroll
        for (int j = 0; j < 6; ++j) {
            fx4 v = *reinterpret_cast<const fx4*>(row + 4 * j);
            h[4*j]=v.x; h[4*j+1]=v.y; h[4*j+2]=v.z; h[4*j+3]=v.w;
        }
        float s = 0.f, s2 = 0.f;
        #pragma unroll
        for (int j = 0; j < 24; ++j) { s += h[j]; s2 = fmaf(h[j], h[j], s2); }
        s  += __shfl_xor(s, 1);  s  += __shfl_xor(s, 2);
        s2 += __shfl_xor(s2, 1); s2 += __shfl_xor(s2, 2);
        const float mu = s * (1.f/CC);
        const float rs = rsqrtf(s2 * (1.f/CC) - mu * mu + LEPS);
        unsigned short t[24];
        #pragma unroll
        for (int j = 0; j < 24; ++j) {
            int c = q4 * 24 + j;
            t[j] = f2bf((h[j] - mu) * rs * g2[c] + b2[c]);
        }
        #pragma unroll
        for (int j = 0; j < 6; ++j) {
            ull_t pk = (ull_t)t[4*j] | ((ull_t)t[4*j+1] << 16) |
                       ((ull_t)t[4*j+2] << 32) | ((ull_t)t[4*j+3] << 48);
            *reinterpret_cast<ull_t*>(&Hn[tl * LDH + q4 * 24 + 4*j]) = pk;
        }
    }

    fx4 oacc[6];
    #pragma unroll
    for (int nt = 0; nt < 6; ++nt) oacc[nt] = (fx4){0.f,0.f,0.f,0.f};

    for (int ck = 0; ck < 6; ++ck) {
        for (int i = tid; i < 64 * 12; i += 512) {       // W1 chunk [64 n][96 k]
            int r = i / 12, k0 = (i - r * 12) * 8;
            *reinterpret_cast<s8v*>(&W1c[r * LDH + k0]) =
                *reinterpret_cast<const s8v*>(&w1t[(ck * 64 + r) * 96 + k0]);
        }
        for (int i = tid; i < 96 * 8; i += 512) {        // W2 chunk [96 n][64 k]
            int r = i / 8, k0 = (i - r * 8) * 8;
            *reinterpret_cast<s8v*>(&W2c[r * LDA + k0]) =
                *reinterpret_cast<const s8v*>(&w2t[r * 384 + ck * 64 + k0]);
        }
        __syncthreads();

        // fc1: each wave computes its 16-token sub-tile
        fx4 a1[4];
        #pragma unroll
        for (int nt = 0; nt < 4; ++nt) a1[nt] = (fx4){0.f,0.f,0.f,0.f};
        #pragma unroll
        for (int ks = 0; ks < 3; ++ks) {
            s8v a = *reinterpret_cast<const s8v*>(&Hn[(wave*16 + l15)*LDH + ks*32 + g4*8]);
            #pragma unroll
            for (int nt = 0; nt < 4; ++nt) {
                s8v b = *reinterpret_cast<const s8v*>(&W1c[(nt*16 + l15)*LDH + ks*32 + g4*8]);
                a1[nt] = MFMA16(a, b, a1[nt]);
            }
        }
        #pragma unroll
        for (int nt = 0; nt < 4; ++nt) {
            const float bb = bf1[ck * 64 + nt * 16 + l15];
            #pragma unroll
            for (int r = 0; r < 4; ++r) {
                float v0 = a1[nt][r] + bb;
                Ac[(wave*16 + g4*4 + r) * LDA + nt*16 + l15] = f2bf(gelu_t(gelu_t(v0)));
            }
        }
        __syncthreads();

        // fc2
        #pragma unroll
        for (int ks = 0; ks < 2; ++ks) {
            s8v a = *reinterpret_cast<const s8v*>(&Ac[(wave*16 + l15)*LDA + ks*32 + g4*8]);
            #pragma unroll
            for (int nt = 0; nt < 6; ++nt) {
                s8v b = *reinterpret_cast<const s8v*>(&W2c[(nt*16 + l15)*LDA + ks*32 + g4*8]);
                oacc[nt] = MFMA16(a, b, oacc[nt]);
            }
        }
        __syncthreads();
    }

    const int rowb = blk * 128 + wave * 16 + g4 * 4;
    #pragma unroll
    for (int nt = 0; nt < 6; ++nt) {
        const int col = nt * 16 + l15;
        const float bb = bf2[col];
        #pragma unroll
        for (int r = 0; r < 4; ++r) {
            const size_t idx = (size_t)(rowb + r) * CC + col;
            xio[idx] = xio[idx] + oacc[nt][r] + bb;
        }
    }
}

extern "C" void kernel_launch(void* const* d_in, const int* in_sizes, int n_in,
                              void* d_out, int out_size, void* d_ws, size_t ws_size,
                              hipStream_t stream)
{
    const float* x    = (const float*)d_in[0];
    const float* n1g  = (const float*)d_in[1];
    const float* n1b  = (const float*)d_in[2];
    const float* qw   = (const float*)d_in[3];
    const float* qb   = (const float*)d_in[4];
    const float* btab = (const float*)d_in[5];
    const float* pw   = (const float*)d_in[6];
    const float* pb   = (const float*)d_in[7];
    const float* n2g  = (const float*)d_in[8];
    const float* n2b  = (const float*)d_in[9];
    const float* w1   = (const float*)d_in[10];
    const float* bf1  = (const float*)d_in[11];
    const float* w2   = (const float*)d_in[12];
    const float* bf2  = (const float*)d_in[13];
    float* out = (float*)d_out;

    float* qkv = (float*)d_ws;                                    // TOT*288 fp32
    unsigned short* wbf = (unsigned short*)((char*)d_ws + (size_t)TOT * 288 * 4);
    unsigned short* qwt = wbf;
    unsigned short* pwt = qwt + 288 * 96;
    unsigned short* w1t = pwt + 96 * 96;
    unsigned short* w2t = w1t + 384 * 96;
    float* bmt = (float*)(wbf + 110592);                          // [4][3][49][64]

    p0_prep <<<579, 256, 0, stream>>>(qw, pw, w1, w2, btab, wbf);
    k1_qkv  <<<TOT/64, 256, 0, stream>>>(x, n1g, n1b, qwt, qb, qkv);
    k2_attn <<<BB*NWIN*NHD, 64, 0, stream>>>(qkv, bmt);
    k2b_proj<<<TOT/64, 256, 0, stream>>>(qkv, pwt, pb, x, out);
    k3_mlp  <<<TOT/128, 512, 0, stream>>>(out, n2g, n2b, w1t, bf1, w2t, bf2);
}

// Round 10
// 155.344 us; speedup vs baseline: 1.4500x; 1.0562x over previous
//
#include <hip/hip_runtime.h>
#include <math.h>

#define BB   32
#define HH   56
#define WWI  56
#define CC   96
#define NHD  3
#define WSZ  7
#define SHF  3
#define NTK  49
#define NWIN 64
#define HDM  32
#define TOT  (BB*HH*WWI)               // 100352
#define QKSCALE 0.17677669529663687f
#define LEPS 1e-3f

typedef __attribute__((ext_vector_type(8))) short s8v;   // 8 bf16 (4 VGPRs)
typedef __attribute__((ext_vector_type(4))) float fx4;   // 4 fp32
typedef unsigned long long ull_t;

#define MFMA16(a,b,c) __builtin_amdgcn_mfma_f32_16x16x32_bf16((a),(b),(c),0,0,0)

__device__ __forceinline__ unsigned short f2bf(float f) {
    union { float f; unsigned u; } v; v.f = f;
    unsigned r = v.u + 0x7FFFu + ((v.u >> 16) & 1u);
    return (unsigned short)(r >> 16);
}

// sigmoid-form gelu (tanh approx): |err vs exact| <~2e-3, ~8 VALU ops vs ~28 for erff
__device__ __forceinline__ float gelu_t(float x) {
    float x3 = x * x * x;
    float z = -1.5957691216f * fmaf(0.044715f, x3, x);
    return x * __builtin_amdgcn_rcpf(1.f + __expf(z));
}

// windowed token id -> original flat token id (roll(-3,-3) + window partition)
__device__ __forceinline__ int wtok_to_orig(int wt) {
    int win = wt / NTK;
    int p   = wt - win * NTK;
    int b   = win >> 6;
    int w   = win & 63;
    int wi = w >> 3, wj = w & 7;
    int pi = p / WSZ, pj = p - pi * WSZ;
    int r = wi * WSZ + pi + SHF; if (r >= HH) r -= HH;
    int c = wj * WSZ + pj + SHF; if (c >= WWI) c -= WWI;
    return b * (HH * WWI) + r * WWI + c;
}

// ---------- P0: weight transpose/bf16 + combined bias+mask table ----------
extern "C" __global__ void p0_prep(const float* __restrict__ qw, const float* __restrict__ pw,
                                   const float* __restrict__ w1, const float* __restrict__ w2,
                                   const float* __restrict__ btab,
                                   unsigned short* __restrict__ wsw)
{
    int i = blockIdx.x * 256 + threadIdx.x;
    if (i < 27648) {                       // qwt[288][96]
        int n = i / 96, k = i - n * 96;
        wsw[i] = f2bf(qw[k * 288 + n]);
    } else if (i < 36864) {                // pwt[96][96]
        int j = i - 27648; int n = j / 96, k = j - n * 96;
        wsw[i] = f2bf(pw[k * 96 + n]);
    } else if (i < 73728) {                // w1t[384][96]
        int j = i - 36864; int n = j / 96, k = j - n * 96;
        wsw[i] = f2bf(w1[k * 384 + n]);
    } else if (i < 110592) {               // w2t[96][384]
        int j = i - 73728; int n = j / 384, k = j - n * 384;
        wsw[i] = f2bf(w2[k * 96 + n]);
    } else if (i < 148224) {               // BM table (fp32)
        float* bm = (float*)(wsw + 110592);
        int j = i - 110592;
        int n = j & 63, mh = j >> 6;
        int m = mh % 49, t = mh / 49;
        int hd = t % 3, cls = t / 3;       // cls = (wi==7)*2 + (wj==7)
        float val = 0.f;
        if (n < 49) {
            int it = m / 7, jt = m - it * 7;
            int iu = n / 7, ju = n - iu * 7;
            int li  = (cls & 2) ? (it < 4 ? 1 : 2) : 0;
            int lj  = (cls & 1) ? (jt < 4 ? 1 : 2) : 0;
            int lui = (cls & 2) ? (iu < 4 ? 1 : 2) : 0;
            int luj = (cls & 1) ? (ju < 4 ? 1 : 2) : 0;
            int bidx = (jt - ju + 6) * 13 + (it - iu + 6);
            val = btab[bidx * 3 + hd] + ((li*3+lj) == (lui*3+luj) ? 0.f : -100.f);
        }
        bm[j] = val;
    }
}

// ---------- K1: gather + LN1 + QKV MFMA GEMM, 512 thr / 128 tokens ----------
#define LDH 104
extern "C" __global__ void __launch_bounds__(512, 4) k1_qkv(
    const float* __restrict__ x, const float* __restrict__ g1, const float* __restrict__ b1,
    const unsigned short* __restrict__ qwt, const float* __restrict__ qb,
    float* __restrict__ qkv)
{
    __shared__ unsigned short Hn[128 * LDH];   // 26624 B (wave-private rows)
    __shared__ unsigned short Wc[96 * LDH];    // 19968 B
    const int tid = threadIdx.x, wave = tid >> 6, lane = tid & 63;
    const int l15 = lane & 15, g4 = lane >> 4;
    const int blk = blockIdx.x;

    { // LN1: 4 lanes per token, 128 tokens
        const int tl = tid >> 2, q4 = tid & 3;
        const int orig = wtok_to_orig(blk * 128 + tl);
        const float* row = x + (size_t)orig * CC + q4 * 24;
        float h[24];
        #pragma unroll
        for (int j = 0; j < 6; ++j) {
            fx4 v = *reinterpret_cast<const fx4*>(row + 4 * j);
            h[4*j]=v.x; h[4*j+1]=v.y; h[4*j+2]=v.z; h[4*j+3]=v.w;
        }
        float s = 0.f, s2 = 0.f;
        #pragma unroll
        for (int j = 0; j < 24; ++j) { s += h[j]; s2 = fmaf(h[j], h[j], s2); }
        s  += __shfl_xor(s, 1);  s  += __shfl_xor(s, 2);
        s2 += __shfl_xor(s2, 1); s2 += __shfl_xor(s2, 2);
        const float mu = s * (1.f/CC);
        const float rs = rsqrtf(s2 * (1.f/CC) - mu * mu + LEPS);
        unsigned short t[24];
        #pragma unroll
        for (int j = 0; j < 24; ++j) {
            int c = q4 * 24 + j;
            t[j] = f2bf((h[j] - mu) * rs * g1[c] + b1[c]);
        }
        #pragma unroll
        for (int j = 0; j < 6; ++j) {
            ull_t pk = (ull_t)t[4*j] | ((ull_t)t[4*j+1] << 16) |
                       ((ull_t)t[4*j+2] << 32) | ((ull_t)t[4*j+3] << 48);
            *reinterpret_cast<ull_t*>(&Hn[tl * LDH + q4 * 24 + 4*j]) = pk;
        }
    }

    for (int ck = 0; ck < 3; ++ck) {
        for (int i = tid; i < 96 * 12; i += 512) {
            int r = i / 12, k0 = (i - r * 12) * 8;
            *reinterpret_cast<s8v*>(&Wc[r * LDH + k0]) =
                *reinterpret_cast<const s8v*>(&qwt[(ck * 96 + r) * 96 + k0]);
        }
        __syncthreads();
        fx4 acc[6];
        #pragma unroll
        for (int nt = 0; nt < 6; ++nt) acc[nt] = (fx4){0.f,0.f,0.f,0.f};
        #pragma unroll
        for (int ks = 0; ks < 3; ++ks) {
            s8v a = *reinterpret_cast<const s8v*>(&Hn[(wave*16 + l15)*LDH + ks*32 + g4*8]);
            #pragma unroll
            for (int nt = 0; nt < 6; ++nt) {
                s8v b = *reinterpret_cast<const s8v*>(&Wc[(nt*16 + l15)*LDH + ks*32 + g4*8]);
                acc[nt] = MFMA16(a, b, acc[nt]);
            }
        }
        const int rowb = blk * 128 + wave * 16 + g4 * 4;
        #pragma unroll
        for (int nt = 0; nt < 6; ++nt) {
            const int col = ck * 96 + nt * 16 + l15;
            const float qbc = qb[col];
            #pragma unroll
            for (int r = 0; r < 4; ++r)
                qkv[(size_t)(rowb + r) * 288 + col] = acc[nt][r] + qbc;
        }
        __syncthreads();
    }
}

// ---------- K2: MFMA attention, 1 wave = 1 (window, head) (unchanged) ----------
extern "C" __global__ void __launch_bounds__(64, 2) k2_attn(
    float* __restrict__ qkv, const float* __restrict__ bm)
{
    __shared__ unsigned short P[64][72];   // 9216 B
    const int lane = threadIdx.x;
    const int l15 = lane & 15, g4 = lane >> 4;
    const int task = blockIdx.x;
    const int win = task / 3, h = task - win * 3;
    const int g0  = win * NTK;
    const int w   = win & 63;
    const int cls = (((w >> 3) == 7) ? 2 : 0) + (((w & 7) == 7) ? 1 : 0);
    const float* BMh = bm + ((size_t)(cls * 3 + h)) * 49 * 64;

    s8v aq[4], bk[4];
    #pragma unroll
    for (int mt = 0; mt < 4; ++mt) {
        int tok = mt * 16 + l15; if (tok > 48) tok = 48;
        const float* qp = &qkv[(size_t)(g0 + tok) * 288 + h * HDM + g4 * 8];
        fx4 v0 = *reinterpret_cast<const fx4*>(qp);
        fx4 v1 = *reinterpret_cast<const fx4*>(qp + 4);
        union { s8v v; unsigned short u[8]; } pa;
        pa.u[0]=f2bf(v0.x*QKSCALE); pa.u[1]=f2bf(v0.y*QKSCALE);
        pa.u[2]=f2bf(v0.z*QKSCALE); pa.u[3]=f2bf(v0.w*QKSCALE);
        pa.u[4]=f2bf(v1.x*QKSCALE); pa.u[5]=f2bf(v1.y*QKSCALE);
        pa.u[6]=f2bf(v1.z*QKSCALE); pa.u[7]=f2bf(v1.w*QKSCALE);
        aq[mt] = pa.v;
        const float* kp = &qkv[(size_t)(g0 + tok) * 288 + 96 + h * HDM + g4 * 8];
        fx4 k0 = *reinterpret_cast<const fx4*>(kp);
        fx4 k1 = *reinterpret_cast<const fx4*>(kp + 4);
        union { s8v v; unsigned short u[8]; } pb;
        pb.u[0]=f2bf(k0.x); pb.u[1]=f2bf(k0.y); pb.u[2]=f2bf(k0.z); pb.u[3]=f2bf(k0.w);
        pb.u[4]=f2bf(k1.x); pb.u[5]=f2bf(k1.y); pb.u[6]=f2bf(k1.z); pb.u[7]=f2bf(k1.w);
        bk[mt] = pb.v;
    }

    fx4 sc[4][4];
    #pragma unroll
    for (int mt = 0; mt < 4; ++mt)
        #pragma unroll
        for (int nt = 0; nt < 4; ++nt)
            sc[mt][nt] = MFMA16(aq[mt], bk[nt], ((fx4){0.f,0.f,0.f,0.f}));

    #pragma unroll
    for (int mt = 0; mt < 4; ++mt) {
        #pragma unroll
        for (int r = 0; r < 4; ++r) {
            const int m = mt * 16 + g4 * 4 + r;
            const int mc = m > 48 ? 48 : m;
            float rs1 = 0.f;
            #pragma unroll
            for (int nt = 0; nt < 4; ++nt) {
                const int n = nt * 16 + l15;
                float s = sc[mt][nt][r] + BMh[mc * 64 + n];
                float e = (n < NTK) ? __expf(s) : 0.f;
                sc[mt][nt][r] = e;
                rs1 += e;
            }
            rs1 += __shfl_xor(rs1, 1); rs1 += __shfl_xor(rs1, 2);
            rs1 += __shfl_xor(rs1, 4); rs1 += __shfl_xor(rs1, 8);
            const float iv1 = 1.f / rs1;
            float rs2 = 0.f;
            #pragma unroll
            for (int nt = 0; nt < 4; ++nt) {
                const int n = nt * 16 + l15;
                float e2 = (n < NTK) ? __expf(sc[mt][nt][r] * iv1) : 0.f;
                sc[mt][nt][r] = e2;
                rs2 += e2;
            }
            rs2 += __shfl_xor(rs2, 1); rs2 += __shfl_xor(rs2, 2);
            rs2 += __shfl_xor(rs2, 4); rs2 += __shfl_xor(rs2, 8);
            const float iv2 = 1.f / rs2;
            #pragma unroll
            for (int nt = 0; nt < 4; ++nt)
                P[m][nt * 16 + l15] = f2bf(sc[mt][nt][r] * iv2);
        }
    }
    __syncthreads();

    fx4 oc[4][2];
    #pragma unroll
    for (int mt = 0; mt < 4; ++mt) { oc[mt][0] = (fx4){0.f,0.f,0.f,0.f}; oc[mt][1] = (fx4){0.f,0.f,0.f,0.f}; }
    #pragma unroll
    for (int ks = 0; ks < 2; ++ks) {
        s8v vb[2];
        #pragma unroll
        for (int nt = 0; nt < 2; ++nt) {
            union { s8v v; unsigned short u[8]; } pv;
            #pragma unroll
            for (int j = 0; j < 8; ++j) {
                int tok = ks * 32 + g4 * 8 + j; if (tok > 48) tok = 48;
                pv.u[j] = f2bf(qkv[(size_t)(g0 + tok) * 288 + 192 + h * HDM + nt * 16 + l15]);
            }
            vb[nt] = pv.v;
        }
        #pragma unroll
        for (int mt = 0; mt < 4; ++mt) {
            s8v pa = *reinterpret_cast<const s8v*>(&P[mt * 16 + l15][ks * 32 + g4 * 8]);
            oc[mt][0] = MFMA16(pa, vb[0], oc[mt][0]);
            oc[mt][1] = MFMA16(pa, vb[1], oc[mt][1]);
        }
    }
    #pragma unroll
    for (int mt = 0; mt < 4; ++mt) {
        #pragma unroll
        for (int r = 0; r < 4; ++r) {
            const int m = mt * 16 + g4 * 4 + r;
            if (m < NTK) {
                qkv[(size_t)(g0 + m) * 288 + h * HDM + l15]      = oc[mt][0][r];
                qkv[(size_t)(g0 + m) * 288 + h * HDM + 16 + l15] = oc[mt][1][r];
            }
        }
    }
}

// ---------- K2b: proj MFMA GEMM + residual + un-shift, 512 thr / 128 tokens ----------
extern "C" __global__ void __launch_bounds__(512, 4) k2b_proj(
    const float* __restrict__ qkv, const unsigned short* __restrict__ pwt,
    const float* __restrict__ pb, const float* __restrict__ x, float* __restrict__ out)
{
    __shared__ unsigned short Ao[128 * LDH];   // 26624 B (wave-private rows)
    __shared__ unsigned short Wc[96 * LDH];    // 19968 B
    const int tid = threadIdx.x, wave = tid >> 6, lane = tid & 63;
    const int l15 = lane & 15, g4 = lane >> 4;
    const int blk = blockIdx.x;

    {
        const int tl = tid >> 2, q4 = tid & 3;
        const float* row = qkv + (size_t)(blk * 128 + tl) * 288 + q4 * 24;
        unsigned short t[24];
        #pragma unroll
        for (int j = 0; j < 6; ++j) {
            fx4 v = *reinterpret_cast<const fx4*>(row + 4 * j);
            t[4*j]=f2bf(v.x); t[4*j+1]=f2bf(v.y); t[4*j+2]=f2bf(v.z); t[4*j+3]=f2bf(v.w);
        }
        #pragma unroll
        for (int j = 0; j < 6; ++j) {
            ull_t pk = (ull_t)t[4*j] | ((ull_t)t[4*j+1] << 16) |
                       ((ull_t)t[4*j+2] << 32) | ((ull_t)t[4*j+3] << 48);
            *reinterpret_cast<ull_t*>(&Ao[tl * LDH + q4 * 24 + 4*j]) = pk;
        }
    }
    for (int i = tid; i < 96 * 12; i += 512) {
        int r = i / 12, k0 = (i - r * 12) * 8;
        *reinterpret_cast<s8v*>(&Wc[r * LDH + k0]) =
            *reinterpret_cast<const s8v*>(&pwt[r * 96 + k0]);
    }
    __syncthreads();

    fx4 acc[6];
    #pragma unroll
    for (int nt = 0; nt < 6; ++nt) acc[nt] = (fx4){0.f,0.f,0.f,0.f};
    #pragma unroll
    for (int ks = 0; ks < 3; ++ks) {
        s8v a = *reinterpret_cast<const s8v*>(&Ao[(wave*16 + l15)*LDH + ks*32 + g4*8]);
        #pragma unroll
        for (int nt = 0; nt < 6; ++nt) {
            s8v b = *reinterpret_cast<const s8v*>(&Wc[(nt*16 + l15)*LDH + ks*32 + g4*8]);
            acc[nt] = MFMA16(a, b, acc[nt]);
        }
    }
    int orig[4];
    #pragma unroll
    for (int r = 0; r < 4; ++r)
        orig[r] = wtok_to_orig(blk * 128 + wave * 16 + g4 * 4 + r);
    #pragma unroll
    for (int nt = 0; nt < 6; ++nt) {
        const int col = nt * 16 + l15;
        const float pbc = pb[col];
        #pragma unroll
        for (int r = 0; r < 4; ++r) {
            const size_t idx = (size_t)orig[r] * CC + col;
            out[idx] = acc[nt][r] + pbc + x[idx];
        }
    }
}

// ---------- K3: LN2 + fc1 + gelu_t^2 + fc2 + residual ----------
// Hn and Ac are wave-private (rows wave*16..+15) -> no barrier between gelu
// write and fc2 read. W staging: T14 split (issue next-ck loads into regs
// before compute, ds_write after the post-fc2 barrier). 2 barriers/ck.
#define LDA 72
// flat weight-stage index -> global load / LDS store (1536 s8v = 3/thread)
#define K3_LD(ck_, idx_, dst_) { \
    if ((idx_) < 768) { int r_ = (idx_) / 12, k0_ = ((idx_) - r_ * 12) * 8; \
        dst_ = *reinterpret_cast<const s8v*>(&w1t[((ck_) * 64 + r_) * 96 + k0_]); } \
    else { int j_ = (idx_) - 768; int r_ = j_ >> 3, k0_ = (j_ & 7) * 8; \
        dst_ = *reinterpret_cast<const s8v*>(&w2t[r_ * 384 + (ck_) * 64 + k0_]); } }
#define K3_ST(idx_, src_) { \
    if ((idx_) < 768) { int r_ = (idx_) / 12, k0_ = ((idx_) - r_ * 12) * 8; \
        *reinterpret_cast<s8v*>(&W1c[r_ * LDH + k0_]) = src_; } \
    else { int j_ = (idx_) - 768; int r_ = j_ >> 3, k0_ = (j_ & 7) * 8; \
        *reinterpret_cast<s8v*>(&W2c[r_ * LDA + k0_]) = src_; } }

extern "C" __global__ void __launch_bounds__(512, 4) k3_mlp(
    float* __restrict__ xio, const float* __restrict__ g2, const float* __restrict__ b2,
    const unsigned short* __restrict__ w1t, const float* __restrict__ bf1,
    const unsigned short* __restrict__ w2t, const float* __restrict__ bf2)
{
    __shared__ unsigned short Hn[128 * LDH];   // 26624 B (wave-private)
    __shared__ unsigned short W1c[64 * LDH];   // 13312 B
    __shared__ unsigned short Ac[128 * LDA];   // 18432 B (wave-private)
    __shared__ unsigned short W2c[96 * LDA];   // 13824 B  (total 72192)
    const int tid = threadIdx.x, wave = tid >> 6, lane = tid & 63;
    const int l15 = lane & 15, g4 = lane >> 4;
    const int blk = blockIdx.x;

    { // LN2: 512 threads x 4 lanes/token = 128 tokens
        const int tl = tid >> 2, q4 = tid & 3;
        const float* row = xio + (size_t)(blk * 128 + tl) * CC + q4 * 24;
        float h[24];
        #pragma unroll
        for (int j = 0; j < 6; ++j) {
            fx4 v = *reinterpret_cast<const fx4*>(row + 4 * j);
            h[4*j]=v.x; h[4*j+1]=v.y; h[4*j+2]=v.z; h[4*j+3]=v.w;
        }
        float s = 0.f, s2 = 0.f;
        #pragma unroll
        for (int j = 0; j < 24; ++j) { s += h[j]; s2 = fmaf(h[j], h[j], s2); }
        s  += __shfl_xor(s, 1);  s  += __shfl_xor(s, 2);
        s2 += __shfl_xor(s2, 1); s2 += __shfl_xor(s2, 2);
        const float mu = s * (1.f/CC);
        const float rs = rsqrtf(s2 * (1.f/CC) - mu * mu + LEPS);
        unsigned short t[24];
        #pragma unroll
        for (int j = 0; j < 24; ++j) {
            int c = q4 * 24 + j;
            t[j] = f2bf((h[j] - mu) * rs * g2[c] + b2[c]);
        }
        #pragma unroll
        for (int j = 0; j < 6; ++j) {
            ull_t pk = (ull_t)t[4*j] | ((ull_t)t[4*j+1] << 16) |
                       ((ull_t)t[4*j+2] << 32) | ((ull_t)t[4*j+3] << 48);
            *reinterpret_cast<ull_t*>(&Hn[tl * LDH + q4 * 24 + 4*j]) = pk;
        }
    }

    // prologue: stage ck=0 weights
    {
        s8v v0, v1, v2;
        K3_LD(0, tid, v0); K3_LD(0, tid + 512, v1); K3_LD(0, tid + 1024, v2);
        K3_ST(tid, v0); K3_ST(tid + 512, v1); K3_ST(tid + 1024, v2);
    }
    __syncthreads();

    fx4 oacc[6];
    #pragma unroll
    for (int nt = 0; nt < 6; ++nt) oacc[nt] = (fx4){0.f,0.f,0.f,0.f};

    for (int ck = 0; ck < 6; ++ck) {
        // T14: issue next chunk's global loads now; they land under compute
        s8v n0, n1, n2;
        if (ck < 5) { K3_LD(ck + 1, tid, n0); K3_LD(ck + 1, tid + 512, n1); K3_LD(ck + 1, tid + 1024, n2); }

        // fc1: each wave computes its 16-token sub-tile
        fx4 a1[4];
        #pragma unroll
        for (int nt = 0; nt < 4; ++nt) a1[nt] = (fx4){0.f,0.f,0.f,0.f};
        #pragma unroll
        for (int ks = 0; ks < 3; ++ks) {
            s8v a = *reinterpret_cast<const s8v*>(&Hn[(wave*16 + l15)*LDH + ks*32 + g4*8]);
            #pragma unroll
            for (int nt = 0; nt < 4; ++nt) {
                s8v b = *reinterpret_cast<const s8v*>(&W1c[(nt*16 + l15)*LDH + ks*32 + g4*8]);
                a1[nt] = MFMA16(a, b, a1[nt]);
            }
        }
        // gelu^2 -> Ac (wave-private rows: NO barrier needed before fc2)
        #pragma unroll
        for (int nt = 0; nt < 4; ++nt) {
            const float bb = bf1[ck * 64 + nt * 16 + l15];
            #pragma unroll
            for (int r = 0; r < 4; ++r) {
                float v0 = a1[nt][r] + bb;
                Ac[(wave*16 + g4*4 + r) * LDA + nt*16 + l15] = f2bf(gelu_t(gelu_t(v0)));
            }
        }
        // fc2
        #pragma unroll
        for (int ks = 0; ks < 2; ++ks) {
            s8v a = *reinterpret_cast<const s8v*>(&Ac[(wave*16 + l15)*LDA + ks*32 + g4*8]);
            #pragma unroll
            for (int nt = 0; nt < 6; ++nt) {
                s8v b = *reinterpret_cast<const s8v*>(&W2c[(nt*16 + l15)*LDA + ks*32 + g4*8]);
                oacc[nt] = MFMA16(a, b, oacc[nt]);
            }
        }
        __syncthreads();                 // all waves done reading W1c/W2c
        if (ck < 5) {
            K3_ST(tid, n0); K3_ST(tid + 512, n1); K3_ST(tid + 1024, n2);
            __syncthreads();             // new W visible to all waves
        }
    }

    const int rowb = blk * 128 + wave * 16 + g4 * 4;
    #pragma unroll
    for (int nt = 0; nt < 6; ++nt) {
        const int col = nt * 16 + l15;
        const float bb = bf2[col];
        #pragma unroll
        for (int r = 0; r < 4; ++r) {
            const size_t idx = (size_t)(rowb + r) * CC + col;
            xio[idx] = xio[idx] + oacc[nt][r] + bb;
        }
    }
}

extern "C" void kernel_launch(void* const* d_in, const int* in_sizes, int n_in,
                              void* d_out, int out_size, void* d_ws, size_t ws_size,
                              hipStream_t stream)
{
    const float* x    = (const float*)d_in[0];
    const float* n1g  = (const float*)d_in[1];
    const float* n1b  = (const float*)d_in[2];
    const float* qw   = (const float*)d_in[3];
    const float* qb   = (const float*)d_in[4];
    const float* btab = (const float*)d_in[5];
    const float* pw   = (const float*)d_in[6];
    const float* pb   = (const float*)d_in[7];
    const float* n2g  = (const float*)d_in[8];
    const float* n2b  = (const float*)d_in[9];
    const float* w1   = (const float*)d_in[10];
    const float* bf1  = (const float*)d_in[11];
    const float* w2   = (const float*)d_in[12];
    const float* bf2  = (const float*)d_in[13];
    float* out = (float*)d_out;

    float* qkv = (float*)d_ws;                                    // TOT*288 fp32
    unsigned short* wbf = (unsigned short*)((char*)d_ws + (size_t)TOT * 288 * 4);
    unsigned short* qwt = wbf;
    unsigned short* pwt = qwt + 288 * 96;
    unsigned short* w1t = pwt + 96 * 96;
    unsigned short* w2t = w1t + 384 * 96;
    float* bmt = (float*)(wbf + 110592);                          // [4][3][49][64]

    p0_prep <<<579, 256, 0, stream>>>(qw, pw, w1, w2, btab, wbf);
    k1_qkv  <<<TOT/128, 512, 0, stream>>>(x, n1g, n1b, qwt, qb, qkv);
    k2_attn <<<BB*NWIN*NHD, 64, 0, stream>>>(qkv, bmt);
    k2b_proj<<<TOT/128, 512, 0, stream>>>(qkv, pwt, pb, x, out);
    k3_mlp  <<<TOT/128, 512, 0, stream>>>(out, n2g, n2b, w1t, bf1, w2t, bf2);
}

// Round 11
// 149.144 us; speedup vs baseline: 1.5103x; 1.0416x over previous
//
#include <hip/hip_runtime.h>
#include <math.h>

#define BB   32
#define HH   56
#define WWI  56
#define CC   96
#define NHD  3
#define WSZ  7
#define SHF  3
#define NTK  49
#define NWIN 64
#define HDM  32
#define TOT  (BB*HH*WWI)               // 100352
#define QKSCALE 0.17677669529663687f
#define LEPS 1e-3f

typedef __attribute__((ext_vector_type(8))) short s8v;   // 8 bf16 (4 VGPRs)
typedef __attribute__((ext_vector_type(4))) float fx4;   // 4 fp32
typedef unsigned long long ull_t;

#define MFMA16(a,b,c) __builtin_amdgcn_mfma_f32_16x16x32_bf16((a),(b),(c),0,0,0)

__device__ __forceinline__ unsigned short f2bf(float f) {
    union { float f; unsigned u; } v; v.f = f;
    unsigned r = v.u + 0x7FFFu + ((v.u >> 16) & 1u);
    return (unsigned short)(r >> 16);
}

// sigmoid-form gelu (tanh approx): |err vs exact| <~2e-3, ~8 VALU ops vs ~28 for erff
__device__ __forceinline__ float gelu_t(float x) {
    float x3 = x * x * x;
    float z = -1.5957691216f * fmaf(0.044715f, x3, x);
    return x * __builtin_amdgcn_rcpf(1.f + __expf(z));
}

// windowed token id -> original flat token id (roll(-3,-3) + window partition)
__device__ __forceinline__ int wtok_to_orig(int wt) {
    int win = wt / NTK;
    int p   = wt - win * NTK;
    int b   = win >> 6;
    int w   = win & 63;
    int wi = w >> 3, wj = w & 7;
    int pi = p / WSZ, pj = p - pi * WSZ;
    int r = wi * WSZ + pi + SHF; if (r >= HH) r -= HH;
    int c = wj * WSZ + pj + SHF; if (c >= WWI) c -= WWI;
    return b * (HH * WWI) + r * WWI + c;
}

// ---------- P0: weight transpose/bf16 (QKSCALE folded into Q cols) + bias+mask ----------
extern "C" __global__ void p0_prep(const float* __restrict__ qw, const float* __restrict__ pw,
                                   const float* __restrict__ w1, const float* __restrict__ w2,
                                   const float* __restrict__ btab,
                                   unsigned short* __restrict__ wsw)
{
    int i = blockIdx.x * 256 + threadIdx.x;
    if (i < 27648) {                       // qwt[288][96]; Q cols (n<96) pre-scaled
        int n = i / 96, k = i - n * 96;
        float v = qw[k * 288 + n];
        if (n < 96) v *= QKSCALE;
        wsw[i] = f2bf(v);
    } else if (i < 36864) {                // pwt[96][96]
        int j = i - 27648; int n = j / 96, k = j - n * 96;
        wsw[i] = f2bf(pw[k * 96 + n]);
    } else if (i < 73728) {                // w1t[384][96]
        int j = i - 36864; int n = j / 96, k = j - n * 96;
        wsw[i] = f2bf(w1[k * 384 + n]);
    } else if (i < 110592) {               // w2t[96][384]
        int j = i - 73728; int n = j / 384, k = j - n * 384;
        wsw[i] = f2bf(w2[k * 96 + n]);
    } else if (i < 148224) {               // BM table (fp32)
        float* bm = (float*)(wsw + 110592);
        int j = i - 110592;
        int n = j & 63, mh = j >> 6;
        int m = mh % 49, t = mh / 49;
        int hd = t % 3, cls = t / 3;       // cls = (wi==7)*2 + (wj==7)
        float val = 0.f;
        if (n < 49) {
            int it = m / 7, jt = m - it * 7;
            int iu = n / 7, ju = n - iu * 7;
            int li  = (cls & 2) ? (it < 4 ? 1 : 2) : 0;
            int lj  = (cls & 1) ? (jt < 4 ? 1 : 2) : 0;
            int lui = (cls & 2) ? (iu < 4 ? 1 : 2) : 0;
            int luj = (cls & 1) ? (ju < 4 ? 1 : 2) : 0;
            int bidx = (jt - ju + 6) * 13 + (it - iu + 6);
            val = btab[bidx * 3 + hd] + ((li*3+lj) == (lui*3+luj) ? 0.f : -100.f);
        }
        bm[j] = val;
    }
}

// ---------- K1: gather + LN1 + QKV MFMA GEMM -> qkvb[TOT][288] bf16 ----------
#define LDH 104
extern "C" __global__ void __launch_bounds__(512, 4) k1_qkv(
    const float* __restrict__ x, const float* __restrict__ g1, const float* __restrict__ b1,
    const unsigned short* __restrict__ qwt, const float* __restrict__ qb,
    unsigned short* __restrict__ qkvb)
{
    __shared__ unsigned short Hn[128 * LDH];   // 26624 B (wave-private rows)
    __shared__ unsigned short Wc[96 * LDH];    // 19968 B
    const int tid = threadIdx.x, wave = tid >> 6, lane = tid & 63;
    const int l15 = lane & 15, g4 = lane >> 4;
    const int blk = blockIdx.x;

    { // LN1: 4 lanes per token, 128 tokens
        const int tl = tid >> 2, q4 = tid & 3;
        const int orig = wtok_to_orig(blk * 128 + tl);
        const float* row = x + (size_t)orig * CC + q4 * 24;
        float h[24];
        #pragma unroll
        for (int j = 0; j < 6; ++j) {
            fx4 v = *reinterpret_cast<const fx4*>(row + 4 * j);
            h[4*j]=v.x; h[4*j+1]=v.y; h[4*j+2]=v.z; h[4*j+3]=v.w;
        }
        float s = 0.f, s2 = 0.f;
        #pragma unroll
        for (int j = 0; j < 24; ++j) { s += h[j]; s2 = fmaf(h[j], h[j], s2); }
        s  += __shfl_xor(s, 1);  s  += __shfl_xor(s, 2);
        s2 += __shfl_xor(s2, 1); s2 += __shfl_xor(s2, 2);
        const float mu = s * (1.f/CC);
        const float rs = rsqrtf(s2 * (1.f/CC) - mu * mu + LEPS);
        unsigned short t[24];
        #pragma unroll
        for (int j = 0; j < 24; ++j) {
            int c = q4 * 24 + j;
            t[j] = f2bf((h[j] - mu) * rs * g1[c] + b1[c]);
        }
        #pragma unroll
        for (int j = 0; j < 6; ++j) {
            ull_t pk = (ull_t)t[4*j] | ((ull_t)t[4*j+1] << 16) |
                       ((ull_t)t[4*j+2] << 32) | ((ull_t)t[4*j+3] << 48);
            *reinterpret_cast<ull_t*>(&Hn[tl * LDH + q4 * 24 + 4*j]) = pk;
        }
    }

    for (int ck = 0; ck < 3; ++ck) {
        for (int i = tid; i < 96 * 12; i += 512) {
            int r = i / 12, k0 = (i - r * 12) * 8;
            *reinterpret_cast<s8v*>(&Wc[r * LDH + k0]) =
                *reinterpret_cast<const s8v*>(&qwt[(ck * 96 + r) * 96 + k0]);
        }
        __syncthreads();
        fx4 acc[6];
        #pragma unroll
        for (int nt = 0; nt < 6; ++nt) acc[nt] = (fx4){0.f,0.f,0.f,0.f};
        #pragma unroll
        for (int ks = 0; ks < 3; ++ks) {
            s8v a = *reinterpret_cast<const s8v*>(&Hn[(wave*16 + l15)*LDH + ks*32 + g4*8]);
            #pragma unroll
            for (int nt = 0; nt < 6; ++nt) {
                s8v b = *reinterpret_cast<const s8v*>(&Wc[(nt*16 + l15)*LDH + ks*32 + g4*8]);
                acc[nt] = MFMA16(a, b, acc[nt]);
            }
        }
        const int rowb = blk * 128 + wave * 16 + g4 * 4;
        const float qmul = (ck == 0) ? QKSCALE : 1.f;   // qb scale matches scaled qwt
        #pragma unroll
        for (int nt = 0; nt < 6; ++nt) {
            const int col = ck * 96 + nt * 16 + l15;
            const float qbc = qb[col] * qmul;
            #pragma unroll
            for (int r = 0; r < 4; ++r)
                qkvb[(size_t)(rowb + r) * 288 + col] = f2bf(acc[nt][r] + qbc);
        }
        __syncthreads();
    }
}

// ---------- K2: MFMA attention on bf16 qkv; frags are direct b128 loads ----------
extern "C" __global__ void __launch_bounds__(64, 2) k2_attn(
    unsigned short* __restrict__ qkvb, const float* __restrict__ bm)
{
    __shared__ unsigned short P[64][72];   // 9216 B
    const int lane = threadIdx.x;
    const int l15 = lane & 15, g4 = lane >> 4;
    const int task = blockIdx.x;
    const int win = task / 3, h = task - win * 3;
    const int g0  = win * NTK;
    const int w   = win & 63;
    const int cls = (((w >> 3) == 7) ? 2 : 0) + (((w & 7) == 7) ? 1 : 0);
    const float* BMh = bm + ((size_t)(cls * 3 + h)) * 49 * 64;

    s8v aq[4], bk[4];
    #pragma unroll
    for (int mt = 0; mt < 4; ++mt) {
        int tok = mt * 16 + l15; if (tok > 48) tok = 48;
        const unsigned short* qp = &qkvb[(size_t)(g0 + tok) * 288 + h * HDM + g4 * 8];
        aq[mt] = *reinterpret_cast<const s8v*>(qp);        // Q (pre-scaled)
        bk[mt] = *reinterpret_cast<const s8v*>(qp + 96);   // K
    }

    fx4 sc[4][4];
    #pragma unroll
    for (int mt = 0; mt < 4; ++mt)
        #pragma unroll
        for (int nt = 0; nt < 4; ++nt)
            sc[mt][nt] = MFMA16(aq[mt], bk[nt], ((fx4){0.f,0.f,0.f,0.f}));

    #pragma unroll
    for (int mt = 0; mt < 4; ++mt) {
        #pragma unroll
        for (int r = 0; r < 4; ++r) {
            const int m = mt * 16 + g4 * 4 + r;
            const int mc = m > 48 ? 48 : m;
            float rs1 = 0.f;
            #pragma unroll
            for (int nt = 0; nt < 4; ++nt) {
                const int n = nt * 16 + l15;
                float s = sc[mt][nt][r] + BMh[mc * 64 + n];
                float e = (n < NTK) ? __expf(s) : 0.f;
                sc[mt][nt][r] = e;
                rs1 += e;
            }
            rs1 += __shfl_xor(rs1, 1); rs1 += __shfl_xor(rs1, 2);
            rs1 += __shfl_xor(rs1, 4); rs1 += __shfl_xor(rs1, 8);
            const float iv1 = 1.f / rs1;
            float rs2 = 0.f;
            #pragma unroll
            for (int nt = 0; nt < 4; ++nt) {
                const int n = nt * 16 + l15;
                float e2 = (n < NTK) ? __expf(sc[mt][nt][r] * iv1) : 0.f;
                sc[mt][nt][r] = e2;
                rs2 += e2;
            }
            rs2 += __shfl_xor(rs2, 1); rs2 += __shfl_xor(rs2, 2);
            rs2 += __shfl_xor(rs2, 4); rs2 += __shfl_xor(rs2, 8);
            const float iv2 = 1.f / rs2;
            #pragma unroll
            for (int nt = 0; nt < 4; ++nt)
                P[m][nt * 16 + l15] = f2bf(sc[mt][nt][r] * iv2);
        }
    }
    __syncthreads();

    fx4 oc[4][2];
    #pragma unroll
    for (int mt = 0; mt < 4; ++mt) { oc[mt][0] = (fx4){0.f,0.f,0.f,0.f}; oc[mt][1] = (fx4){0.f,0.f,0.f,0.f}; }
    #pragma unroll
    for (int ks = 0; ks < 2; ++ks) {
        s8v vb[2];
        #pragma unroll
        for (int nt = 0; nt < 2; ++nt) {
            union { s8v v; unsigned short u[8]; } pv;
            #pragma unroll
            for (int j = 0; j < 8; ++j) {
                int tok = ks * 32 + g4 * 8 + j; if (tok > 48) tok = 48;
                pv.u[j] = qkvb[(size_t)(g0 + tok) * 288 + 192 + h * HDM + nt * 16 + l15];
            }
            vb[nt] = pv.v;
        }
        #pragma unroll
        for (int mt = 0; mt < 4; ++mt) {
            s8v pa = *reinterpret_cast<const s8v*>(&P[mt * 16 + l15][ks * 32 + g4 * 8]);
            oc[mt][0] = MFMA16(pa, vb[0], oc[mt][0]);
            oc[mt][1] = MFMA16(pa, vb[1], oc[mt][1]);
        }
    }
    #pragma unroll
    for (int mt = 0; mt < 4; ++mt) {
        #pragma unroll
        for (int r = 0; r < 4; ++r) {
            const int m = mt * 16 + g4 * 4 + r;
            if (m < NTK) {
                qkvb[(size_t)(g0 + m) * 288 + h * HDM + l15]      = f2bf(oc[mt][0][r]);
                qkvb[(size_t)(g0 + m) * 288 + h * HDM + 16 + l15] = f2bf(oc[mt][1][r]);
            }
        }
    }
}

// ---------- K2b: proj MFMA GEMM + residual + un-shift, bf16 O input ----------
extern "C" __global__ void __launch_bounds__(512, 4) k2b_proj(
    const unsigned short* __restrict__ qkvb, const unsigned short* __restrict__ pwt,
    const float* __restrict__ pb, const float* __restrict__ x, float* __restrict__ out)
{
    __shared__ unsigned short Ao[128 * LDH];   // 26624 B (wave-private rows)
    __shared__ unsigned short Wc[96 * LDH];    // 19968 B
    const int tid = threadIdx.x, wave = tid >> 6, lane = tid & 63;
    const int l15 = lane & 15, g4 = lane >> 4;
    const int blk = blockIdx.x;

    {   // stage O tile: direct bf16 copy (no conversion)
        const int tl = tid >> 2, q4 = tid & 3;
        const unsigned short* row = qkvb + (size_t)(blk * 128 + tl) * 288 + q4 * 24;
        #pragma unroll
        for (int j = 0; j < 3; ++j)
            *reinterpret_cast<s8v*>(&Ao[tl * LDH + q4 * 24 + j * 8]) =
                *reinterpret_cast<const s8v*>(row + j * 8);
    }
    for (int i = tid; i < 96 * 12; i += 512) {
        int r = i / 12, k0 = (i - r * 12) * 8;
        *reinterpret_cast<s8v*>(&Wc[r * LDH + k0]) =
            *reinterpret_cast<const s8v*>(&pwt[r * 96 + k0]);
    }
    __syncthreads();

    fx4 acc[6];
    #pragma unroll
    for (int nt = 0; nt < 6; ++nt) acc[nt] = (fx4){0.f,0.f,0.f,0.f};
    #pragma unroll
    for (int ks = 0; ks < 3; ++ks) {
        s8v a = *reinterpret_cast<const s8v*>(&Ao[(wave*16 + l15)*LDH + ks*32 + g4*8]);
        #pragma unroll
        for (int nt = 0; nt < 6; ++nt) {
            s8v b = *reinterpret_cast<const s8v*>(&Wc[(nt*16 + l15)*LDH + ks*32 + g4*8]);
            acc[nt] = MFMA16(a, b, acc[nt]);
        }
    }
    int orig[4];
    #pragma unroll
    for (int r = 0; r < 4; ++r)
        orig[r] = wtok_to_orig(blk * 128 + wave * 16 + g4 * 4 + r);
    #pragma unroll
    for (int nt = 0; nt < 6; ++nt) {
        const int col = nt * 16 + l15;
        const float pbc = pb[col];
        #pragma unroll
        for (int r = 0; r < 4; ++r) {
            const size_t idx = (size_t)orig[r] * CC + col;
            out[idx] = acc[nt][r] + pbc + x[idx];
        }
    }
}

// ---------- K3: LN2 + fc1 + gelu_t^2 + fc2 + residual (R10 structure) ----------
#define LDA 72
#define K3_LD(ck_, idx_, dst_) { \
    if ((idx_) < 768) { int r_ = (idx_) / 12, k0_ = ((idx_) - r_ * 12) * 8; \
        dst_ = *reinterpret_cast<const s8v*>(&w1t[((ck_) * 64 + r_) * 96 + k0_]); } \
    else { int j_ = (idx_) - 768; int r_ = j_ >> 3, k0_ = (j_ & 7) * 8; \
        dst_ = *reinterpret_cast<const s8v*>(&w2t[r_ * 384 + (ck_) * 64 + k0_]); } }
#define K3_ST(idx_, src_) { \
    if ((idx_) < 768) { int r_ = (idx_) / 12, k0_ = ((idx_) - r_ * 12) * 8; \
        *reinterpret_cast<s8v*>(&W1c[r_ * LDH + k0_]) = src_; } \
    else { int j_ = (idx_) - 768; int r_ = j_ >> 3, k0_ = (j_ & 7) * 8; \
        *reinterpret_cast<s8v*>(&W2c[r_ * LDA + k0_]) = src_; } }

extern "C" __global__ void __launch_bounds__(512, 4) k3_mlp(
    float* __restrict__ xio, const float* __restrict__ g2, const float* __restrict__ b2,
    const unsigned short* __restrict__ w1t, const float* __restrict__ bf1,
    const unsigned short* __restrict__ w2t, const float* __restrict__ bf2)
{
    __shared__ unsigned short Hn[128 * LDH];   // 26624 B (wave-private)
    __shared__ unsigned short W1c[64 * LDH];   // 13312 B
    __shared__ unsigned short Ac[128 * LDA];   // 18432 B (wave-private)
    __shared__ unsigned short W2c[96 * LDA];   // 13824 B  (total 72192)
    const int tid = threadIdx.x, wave = tid >> 6, lane = tid & 63;
    const int l15 = lane & 15, g4 = lane >> 4;
    const int blk = blockIdx.x;

    { // LN2: 512 threads x 4 lanes/token = 128 tokens
        const int tl = tid >> 2, q4 = tid & 3;
        const float* row = xio + (size_t)(blk * 128 + tl) * CC + q4 * 24;
        float h[24];
        #pragma unroll
        for (int j = 0; j < 6; ++j) {
            fx4 v = *reinterpret_cast<const fx4*>(row + 4 * j);
            h[4*j]=v.x; h[4*j+1]=v.y; h[4*j+2]=v.z; h[4*j+3]=v.w;
        }
        float s = 0.f, s2 = 0.f;
        #pragma unroll
        for (int j = 0; j < 24; ++j) { s += h[j]; s2 = fmaf(h[j], h[j], s2); }
        s  += __shfl_xor(s, 1);  s  += __shfl_xor(s, 2);
        s2 += __shfl_xor(s2, 1); s2 += __shfl_xor(s2, 2);
        const float mu = s * (1.f/CC);
        const float rs = rsqrtf(s2 * (1.f/CC) - mu * mu + LEPS);
        unsigned short t[24];
        #pragma unroll
        for (int j = 0; j < 24; ++j) {
            int c = q4 * 24 + j;
            t[j] = f2bf((h[j] - mu) * rs * g2[c] + b2[c]);
        }
        #pragma unroll
        for (int j = 0; j < 6; ++j) {
            ull_t pk = (ull_t)t[4*j] | ((ull_t)t[4*j+1] << 16) |
                       ((ull_t)t[4*j+2] << 32) | ((ull_t)t[4*j+3] << 48);
            *reinterpret_cast<ull_t*>(&Hn[tl * LDH + q4 * 24 + 4*j]) = pk;
        }
    }

    { // prologue: stage ck=0 weights
        s8v v0, v1, v2;
        K3_LD(0, tid, v0); K3_LD(0, tid + 512, v1); K3_LD(0, tid + 1024, v2);
        K3_ST(tid, v0); K3_ST(tid + 512, v1); K3_ST(tid + 1024, v2);
    }
    __syncthreads();

    fx4 oacc[6];
    #pragma unroll
    for (int nt = 0; nt < 6; ++nt) oacc[nt] = (fx4){0.f,0.f,0.f,0.f};

    for (int ck = 0; ck < 6; ++ck) {
        s8v n0, n1, n2;
        if (ck < 5) { K3_LD(ck + 1, tid, n0); K3_LD(ck + 1, tid + 512, n1); K3_LD(ck + 1, tid + 1024, n2); }

        fx4 a1[4];
        #pragma unroll
        for (int nt = 0; nt < 4; ++nt) a1[nt] = (fx4){0.f,0.f,0.f,0.f};
        #pragma unroll
        for (int ks = 0; ks < 3; ++ks) {
            s8v a = *reinterpret_cast<const s8v*>(&Hn[(wave*16 + l15)*LDH + ks*32 + g4*8]);
            #pragma unroll
            for (int nt = 0; nt < 4; ++nt) {
                s8v b = *reinterpret_cast<const s8v*>(&W1c[(nt*16 + l15)*LDH + ks*32 + g4*8]);
                a1[nt] = MFMA16(a, b, a1[nt]);
            }
        }
        #pragma unroll
        for (int nt = 0; nt < 4; ++nt) {
            const float bb = bf1[ck * 64 + nt * 16 + l15];
            #pragma unroll
            for (int r = 0; r < 4; ++r) {
                float v0 = a1[nt][r] + bb;
                Ac[(wave*16 + g4*4 + r) * LDA + nt*16 + l15] = f2bf(gelu_t(gelu_t(v0)));
            }
        }
        #pragma unroll
        for (int ks = 0; ks < 2; ++ks) {
            s8v a = *reinterpret_cast<const s8v*>(&Ac[(wave*16 + l15)*LDA + ks*32 + g4*8]);
            #pragma unroll
            for (int nt = 0; nt < 6; ++nt) {
                s8v b = *reinterpret_cast<const s8v*>(&W2c[(nt*16 + l15)*LDA + ks*32 + g4*8]);
                oacc[nt] = MFMA16(a, b, oacc[nt]);
            }
        }
        __syncthreads();
        if (ck < 5) {
            K3_ST(tid, n0); K3_ST(tid + 512, n1); K3_ST(tid + 1024, n2);
            __syncthreads();
        }
    }

    const int rowb = blk * 128 + wave * 16 + g4 * 4;
    #pragma unroll
    for (int nt = 0; nt < 6; ++nt) {
        const int col = nt * 16 + l15;
        const float bb = bf2[col];
        #pragma unroll
        for (int r = 0; r < 4; ++r) {
            const size_t idx = (size_t)(rowb + r) * CC + col;
            xio[idx] = xio[idx] + oacc[nt][r] + bb;
        }
    }
}

extern "C" void kernel_launch(void* const* d_in, const int* in_sizes, int n_in,
                              void* d_out, int out_size, void* d_ws, size_t ws_size,
                              hipStream_t stream)
{
    const float* x    = (const float*)d_in[0];
    const float* n1g  = (const float*)d_in[1];
    const float* n1b  = (const float*)d_in[2];
    const float* qw   = (const float*)d_in[3];
    const float* qb   = (const float*)d_in[4];
    const float* btab = (const float*)d_in[5];
    const float* pw   = (const float*)d_in[6];
    const float* pb   = (const float*)d_in[7];
    const float* n2g  = (const float*)d_in[8];
    const float* n2b  = (const float*)d_in[9];
    const float* w1   = (const float*)d_in[10];
    const float* bf1  = (const float*)d_in[11];
    const float* w2   = (const float*)d_in[12];
    const float* bf2  = (const float*)d_in[13];
    float* out = (float*)d_out;

    unsigned short* qkvb = (unsigned short*)d_ws;                 // TOT*288 bf16 = 57.8 MB
    unsigned short* wbf = qkvb + (size_t)TOT * 288;
    unsigned short* qwt = wbf;
    unsigned short* pwt = qwt + 288 * 96;
    unsigned short* w1t = pwt + 96 * 96;
    unsigned short* w2t = w1t + 384 * 96;
    float* bmt = (float*)(wbf + 110592);                          // [4][3][49][64]

    p0_prep <<<579, 256, 0, stream>>>(qw, pw, w1, w2, btab, wbf);
    k1_qkv  <<<TOT/128, 512, 0, stream>>>(x, n1g, n1b, qwt, qb, qkvb);
    k2_attn <<<BB*NWIN*NHD, 64, 0, stream>>>(qkvb, bmt);
    k2b_proj<<<TOT/128, 512, 0, stream>>>(qkvb, pwt, pb, x, out);
    k3_mlp  <<<TOT/128, 512, 0, stream>>>(out, n2g, n2b, w1t, bf1, w2t, bf2);
}

// Round 12
// 146.415 us; speedup vs baseline: 1.5384x; 1.0186x over previous
//
#include <hip/hip_runtime.h>
#include <math.h>

#define BB   32
#define HH   56
#define WWI  56
#define CC   96
#define NHD  3
#define WSZ  7
#define SHF  3
#define NTK  49
#define NWIN 64
#define HDM  32
#define TOT  (BB*HH*WWI)               // 100352
#define QKSCALE 0.17677669529663687f
#define LEPS 1e-3f

typedef __attribute__((ext_vector_type(8))) short s8v;   // 8 bf16 (4 VGPRs)
typedef __attribute__((ext_vector_type(4))) float fx4;   // 4 fp32
typedef unsigned long long ull_t;

#define MFMA16(a,b,c) __builtin_amdgcn_mfma_f32_16x16x32_bf16((a),(b),(c),0,0,0)

__device__ __forceinline__ unsigned short f2bf(float f) {
    union { float f; unsigned u; } v; v.f = f;
    unsigned r = v.u + 0x7FFFu + ((v.u >> 16) & 1u);
    return (unsigned short)(r >> 16);
}

// sigmoid-form gelu (tanh approx): |err vs exact| <~2e-3, ~8 VALU ops vs ~28 for erff
__device__ __forceinline__ float gelu_t(float x) {
    float x3 = x * x * x;
    float z = -1.5957691216f * fmaf(0.044715f, x3, x);
    return x * __builtin_amdgcn_rcpf(1.f + __expf(z));
}

// windowed token id -> original flat token id (roll(-3,-3) + window partition)
__device__ __forceinline__ int wtok_to_orig(int wt) {
    int win = wt / NTK;
    int p   = wt - win * NTK;
    int b   = win >> 6;
    int w   = win & 63;
    int wi = w >> 3, wj = w & 7;
    int pi = p / WSZ, pj = p - pi * WSZ;
    int r = wi * WSZ + pi + SHF; if (r >= HH) r -= HH;
    int c = wj * WSZ + pj + SHF; if (c >= WWI) c -= WWI;
    return b * (HH * WWI) + r * WWI + c;
}

// LayerNorm in MFMA-A-fragment layout: lane (l15,g4) owns token's k-chunks
// {ks*32+g4*8 .. +7}; reduction across the 4 g4-groups via shfl_xor(16/32).
// Produces 3 s8v A-fragments in registers -> no LDS staging for A at all.
__device__ __forceinline__ void ln_frag(const float* __restrict__ row,
                                        const float* __restrict__ gg,
                                        const float* __restrict__ bb,
                                        int g4, s8v ha[3])
{
    float h[24];
    #pragma unroll
    for (int ks = 0; ks < 3; ++ks) {
        fx4 v0 = *reinterpret_cast<const fx4*>(row + ks * 32 + g4 * 8);
        fx4 v1 = *reinterpret_cast<const fx4*>(row + ks * 32 + g4 * 8 + 4);
        h[ks*8+0]=v0.x; h[ks*8+1]=v0.y; h[ks*8+2]=v0.z; h[ks*8+3]=v0.w;
        h[ks*8+4]=v1.x; h[ks*8+5]=v1.y; h[ks*8+6]=v1.z; h[ks*8+7]=v1.w;
    }
    float s = 0.f, s2 = 0.f;
    #pragma unroll
    for (int j = 0; j < 24; ++j) { s += h[j]; s2 = fmaf(h[j], h[j], s2); }
    s  += __shfl_xor(s, 16);  s  += __shfl_xor(s, 32);
    s2 += __shfl_xor(s2, 16); s2 += __shfl_xor(s2, 32);
    const float mu = s * (1.f/CC);
    const float rs = rsqrtf(s2 * (1.f/CC) - mu * mu + LEPS);
    #pragma unroll
    for (int ks = 0; ks < 3; ++ks) {
        union { s8v v; unsigned short u[8]; } p;
        #pragma unroll
        for (int j = 0; j < 8; ++j) {
            int c = ks * 32 + g4 * 8 + j;
            p.u[j] = f2bf((h[ks*8+j] - mu) * rs * gg[c] + bb[c]);
        }
        ha[ks] = p.v;
    }
}

// ---------- P0: weight transpose/bf16 (QKSCALE folded into Q cols) + bias+mask ----------
extern "C" __global__ void p0_prep(const float* __restrict__ qw, const float* __restrict__ pw,
                                   const float* __restrict__ w1, const float* __restrict__ w2,
                                   const float* __restrict__ btab,
                                   unsigned short* __restrict__ wsw)
{
    int i = blockIdx.x * 256 + threadIdx.x;
    if (i < 27648) {                       // qwt[288][96]; Q cols (n<96) pre-scaled
        int n = i / 96, k = i - n * 96;
        float v = qw[k * 288 + n];
        if (n < 96) v *= QKSCALE;
        wsw[i] = f2bf(v);
    } else if (i < 36864) {                // pwt[96][96]
        int j = i - 27648; int n = j / 96, k = j - n * 96;
        wsw[i] = f2bf(pw[k * 96 + n]);
    } else if (i < 73728) {                // w1t[384][96]
        int j = i - 36864; int n = j / 96, k = j - n * 96;
        wsw[i] = f2bf(w1[k * 384 + n]);
    } else if (i < 110592) {               // w2t[96][384]
        int j = i - 73728; int n = j / 384, k = j - n * 384;
        wsw[i] = f2bf(w2[k * 96 + n]);
    } else if (i < 148224) {               // BM table (fp32)
        float* bm = (float*)(wsw + 110592);
        int j = i - 110592;
        int n = j & 63, mh = j >> 6;
        int m = mh % 49, t = mh / 49;
        int hd = t % 3, cls = t / 3;       // cls = (wi==7)*2 + (wj==7)
        float val = 0.f;
        if (n < 49) {
            int it = m / 7, jt = m - it * 7;
            int iu = n / 7, ju = n - iu * 7;
            int li  = (cls & 2) ? (it < 4 ? 1 : 2) : 0;
            int lj  = (cls & 1) ? (jt < 4 ? 1 : 2) : 0;
            int lui = (cls & 2) ? (iu < 4 ? 1 : 2) : 0;
            int luj = (cls & 1) ? (ju < 4 ? 1 : 2) : 0;
            int bidx = (jt - ju + 6) * 13 + (it - iu + 6);
            val = btab[bidx * 3 + hd] + ((li*3+lj) == (lui*3+luj) ? 0.f : -100.f);
        }
        bm[j] = val;
    }
}

// ---------- K1: gather + LN1(frag) + QKV MFMA GEMM -> qkvb bf16; LDS = Wc only ----------
#define LDH 104
extern "C" __global__ void __launch_bounds__(512, 4) k1_qkv(
    const float* __restrict__ x, const float* __restrict__ g1, const float* __restrict__ b1,
    const unsigned short* __restrict__ qwt, const float* __restrict__ qb,
    unsigned short* __restrict__ qkvb)
{
    __shared__ unsigned short Wc[96 * LDH];    // 19968 B
    const int tid = threadIdx.x, wave = tid >> 6, lane = tid & 63;
    const int l15 = lane & 15, g4 = lane >> 4;
    const int blk = blockIdx.x;

    s8v ha[3];
    {
        const int orig = wtok_to_orig(blk * 128 + wave * 16 + l15);
        ln_frag(x + (size_t)orig * CC, g1, b1, g4, ha);
    }

    for (int ck = 0; ck < 3; ++ck) {
        for (int i = tid; i < 96 * 12; i += 512) {
            int r = i / 12, k0 = (i - r * 12) * 8;
            *reinterpret_cast<s8v*>(&Wc[r * LDH + k0]) =
                *reinterpret_cast<const s8v*>(&qwt[(ck * 96 + r) * 96 + k0]);
        }
        __syncthreads();
        fx4 acc[6];
        #pragma unroll
        for (int nt = 0; nt < 6; ++nt) acc[nt] = (fx4){0.f,0.f,0.f,0.f};
        #pragma unroll
        for (int ks = 0; ks < 3; ++ks) {
            #pragma unroll
            for (int nt = 0; nt < 6; ++nt) {
                s8v b = *reinterpret_cast<const s8v*>(&Wc[(nt*16 + l15)*LDH + ks*32 + g4*8]);
                acc[nt] = MFMA16(ha[ks], b, acc[nt]);
            }
        }
        const int rowb = blk * 128 + wave * 16 + g4 * 4;
        const float qmul = (ck == 0) ? QKSCALE : 1.f;   // qb scale matches scaled qwt
        #pragma unroll
        for (int nt = 0; nt < 6; ++nt) {
            const int col = ck * 96 + nt * 16 + l15;
            const float qbc = qb[col] * qmul;
            #pragma unroll
            for (int r = 0; r < 4; ++r)
                qkvb[(size_t)(rowb + r) * 288 + col] = f2bf(acc[nt][r] + qbc);
        }
        __syncthreads();
    }
}

// ---------- K2: MFMA attention on bf16 qkv (unchanged from R11) ----------
extern "C" __global__ void __launch_bounds__(64, 2) k2_attn(
    unsigned short* __restrict__ qkvb, const float* __restrict__ bm)
{
    __shared__ unsigned short P[64][72];   // 9216 B
    const int lane = threadIdx.x;
    const int l15 = lane & 15, g4 = lane >> 4;
    const int task = blockIdx.x;
    const int win = task / 3, h = task - win * 3;
    const int g0  = win * NTK;
    const int w   = win & 63;
    const int cls = (((w >> 3) == 7) ? 2 : 0) + (((w & 7) == 7) ? 1 : 0);
    const float* BMh = bm + ((size_t)(cls * 3 + h)) * 49 * 64;

    s8v aq[4], bk[4];
    #pragma unroll
    for (int mt = 0; mt < 4; ++mt) {
        int tok = mt * 16 + l15; if (tok > 48) tok = 48;
        const unsigned short* qp = &qkvb[(size_t)(g0 + tok) * 288 + h * HDM + g4 * 8];
        aq[mt] = *reinterpret_cast<const s8v*>(qp);        // Q (pre-scaled)
        bk[mt] = *reinterpret_cast<const s8v*>(qp + 96);   // K
    }

    fx4 sc[4][4];
    #pragma unroll
    for (int mt = 0; mt < 4; ++mt)
        #pragma unroll
        for (int nt = 0; nt < 4; ++nt)
            sc[mt][nt] = MFMA16(aq[mt], bk[nt], ((fx4){0.f,0.f,0.f,0.f}));

    #pragma unroll
    for (int mt = 0; mt < 4; ++mt) {
        #pragma unroll
        for (int r = 0; r < 4; ++r) {
            const int m = mt * 16 + g4 * 4 + r;
            const int mc = m > 48 ? 48 : m;
            float rs1 = 0.f;
            #pragma unroll
            for (int nt = 0; nt < 4; ++nt) {
                const int n = nt * 16 + l15;
                float s = sc[mt][nt][r] + BMh[mc * 64 + n];
                float e = (n < NTK) ? __expf(s) : 0.f;
                sc[mt][nt][r] = e;
                rs1 += e;
            }
            rs1 += __shfl_xor(rs1, 1); rs1 += __shfl_xor(rs1, 2);
            rs1 += __shfl_xor(rs1, 4); rs1 += __shfl_xor(rs1, 8);
            const float iv1 = 1.f / rs1;
            float rs2 = 0.f;
            #pragma unroll
            for (int nt = 0; nt < 4; ++nt) {
                const int n = nt * 16 + l15;
                float e2 = (n < NTK) ? __expf(sc[mt][nt][r] * iv1) : 0.f;
                sc[mt][nt][r] = e2;
                rs2 += e2;
            }
            rs2 += __shfl_xor(rs2, 1); rs2 += __shfl_xor(rs2, 2);
            rs2 += __shfl_xor(rs2, 4); rs2 += __shfl_xor(rs2, 8);
            const float iv2 = 1.f / rs2;
            #pragma unroll
            for (int nt = 0; nt < 4; ++nt)
                P[m][nt * 16 + l15] = f2bf(sc[mt][nt][r] * iv2);
        }
    }
    __syncthreads();

    fx4 oc[4][2];
    #pragma unroll
    for (int mt = 0; mt < 4; ++mt) { oc[mt][0] = (fx4){0.f,0.f,0.f,0.f}; oc[mt][1] = (fx4){0.f,0.f,0.f,0.f}; }
    #pragma unroll
    for (int ks = 0; ks < 2; ++ks) {
        s8v vb[2];
        #pragma unroll
        for (int nt = 0; nt < 2; ++nt) {
            union { s8v v; unsigned short u[8]; } pv;
            #pragma unroll
            for (int j = 0; j < 8; ++j) {
                int tok = ks * 32 + g4 * 8 + j; if (tok > 48) tok = 48;
                pv.u[j] = qkvb[(size_t)(g0 + tok) * 288 + 192 + h * HDM + nt * 16 + l15];
            }
            vb[nt] = pv.v;
        }
        #pragma unroll
        for (int mt = 0; mt < 4; ++mt) {
            s8v pa = *reinterpret_cast<const s8v*>(&P[mt * 16 + l15][ks * 32 + g4 * 8]);
            oc[mt][0] = MFMA16(pa, vb[0], oc[mt][0]);
            oc[mt][1] = MFMA16(pa, vb[1], oc[mt][1]);
        }
    }
    #pragma unroll
    for (int mt = 0; mt < 4; ++mt) {
        #pragma unroll
        for (int r = 0; r < 4; ++r) {
            const int m = mt * 16 + g4 * 4 + r;
            if (m < NTK) {
                qkvb[(size_t)(g0 + m) * 288 + h * HDM + l15]      = f2bf(oc[mt][0][r]);
                qkvb[(size_t)(g0 + m) * 288 + h * HDM + 16 + l15] = f2bf(oc[mt][1][r]);
            }
        }
    }
}

// ---------- K2b: proj GEMM; A-frags DIRECT from qkvb (bf16, frag-ready); LDS = Wc ----------
extern "C" __global__ void __launch_bounds__(512, 4) k2b_proj(
    const unsigned short* __restrict__ qkvb, const unsigned short* __restrict__ pwt,
    const float* __restrict__ pb, const float* __restrict__ x, float* __restrict__ out)
{
    __shared__ unsigned short Wc[96 * LDH];    // 19968 B
    const int tid = threadIdx.x, wave = tid >> 6, lane = tid & 63;
    const int l15 = lane & 15, g4 = lane >> 4;
    const int blk = blockIdx.x;

    for (int i = tid; i < 96 * 12; i += 512) {
        int r = i / 12, k0 = (i - r * 12) * 8;
        *reinterpret_cast<s8v*>(&Wc[r * LDH + k0]) =
            *reinterpret_cast<const s8v*>(&pwt[r * 96 + k0]);
    }
    const unsigned short* arow = qkvb + (size_t)(blk * 128 + wave * 16 + l15) * 288 + g4 * 8;
    s8v a0 = *reinterpret_cast<const s8v*>(arow);
    s8v a1 = *reinterpret_cast<const s8v*>(arow + 32);
    s8v a2 = *reinterpret_cast<const s8v*>(arow + 64);
    __syncthreads();

    fx4 acc[6];
    #pragma unroll
    for (int nt = 0; nt < 6; ++nt) acc[nt] = (fx4){0.f,0.f,0.f,0.f};
    #pragma unroll
    for (int nt = 0; nt < 6; ++nt) {
        acc[nt] = MFMA16(a0, *reinterpret_cast<const s8v*>(&Wc[(nt*16 + l15)*LDH +  0 + g4*8]), acc[nt]);
        acc[nt] = MFMA16(a1, *reinterpret_cast<const s8v*>(&Wc[(nt*16 + l15)*LDH + 32 + g4*8]), acc[nt]);
        acc[nt] = MFMA16(a2, *reinterpret_cast<const s8v*>(&Wc[(nt*16 + l15)*LDH + 64 + g4*8]), acc[nt]);
    }
    int orig[4];
    #pragma unroll
    for (int r = 0; r < 4; ++r)
        orig[r] = wtok_to_orig(blk * 128 + wave * 16 + g4 * 4 + r);
    #pragma unroll
    for (int nt = 0; nt < 6; ++nt) {
        const int col = nt * 16 + l15;
        const float pbc = pb[col];
        #pragma unroll
        for (int r = 0; r < 4; ++r) {
            const size_t idx = (size_t)orig[r] * CC + col;
            out[idx] = acc[nt][r] + pbc + x[idx];
        }
    }
}

// ---------- K3: LN2(frag) + fc1 + gelu_t^2 + fc2 + residual; LDS = W1c|Ac|W2c ----------
#define LDA 72
#define K3_LD(ck_, idx_, dst_) { \
    if ((idx_) < 768) { int r_ = (idx_) / 12, k0_ = ((idx_) - r_ * 12) * 8; \
        dst_ = *reinterpret_cast<const s8v*>(&w1t[((ck_) * 64 + r_) * 96 + k0_]); } \
    else { int j_ = (idx_) - 768; int r_ = j_ >> 3, k0_ = (j_ & 7) * 8; \
        dst_ = *reinterpret_cast<const s8v*>(&w2t[r_ * 384 + (ck_) * 64 + k0_]); } }
#define K3_ST(idx_, src_) { \
    if ((idx_) < 768) { int r_ = (idx_) / 12, k0_ = ((idx_) - r_ * 12) * 8; \
        *reinterpret_cast<s8v*>(&W1c[r_ * LDH + k0_]) = src_; } \
    else { int j_ = (idx_) - 768; int r_ = j_ >> 3, k0_ = (j_ & 7) * 8; \
        *reinterpret_cast<s8v*>(&W2c[r_ * LDA + k0_]) = src_; } }

extern "C" __global__ void __launch_bounds__(512, 4) k3_mlp(
    float* __restrict__ xio, const float* __restrict__ g2, const float* __restrict__ b2,
    const unsigned short* __restrict__ w1t, const float* __restrict__ bf1,
    const unsigned short* __restrict__ w2t, const float* __restrict__ bf2)
{
    __shared__ unsigned short W1c[64 * LDH];   // 13312 B
    __shared__ unsigned short Ac[128 * LDA];   // 18432 B (wave-private)
    __shared__ unsigned short W2c[96 * LDA];   // 13824 B  (total 45568 -> 3 blocks/CU)
    const int tid = threadIdx.x, wave = tid >> 6, lane = tid & 63;
    const int l15 = lane & 15, g4 = lane >> 4;
    const int blk = blockIdx.x;

    s8v ha[3];
    ln_frag(xio + (size_t)(blk * 128 + wave * 16 + l15) * CC, g2, b2, g4, ha);

    { // prologue: stage ck=0 weights
        s8v v0, v1, v2;
        K3_LD(0, tid, v0); K3_LD(0, tid + 512, v1); K3_LD(0, tid + 1024, v2);
        K3_ST(tid, v0); K3_ST(tid + 512, v1); K3_ST(tid + 1024, v2);
    }
    __syncthreads();

    fx4 oacc[6];
    #pragma unroll
    for (int nt = 0; nt < 6; ++nt) oacc[nt] = (fx4){0.f,0.f,0.f,0.f};

    for (int ck = 0; ck < 6; ++ck) {
        s8v n0, n1, n2;
        if (ck < 5) { K3_LD(ck + 1, tid, n0); K3_LD(ck + 1, tid + 512, n1); K3_LD(ck + 1, tid + 1024, n2); }

        // fc1: A from registers (ha), B from W1c
        fx4 a1[4];
        #pragma unroll
        for (int nt = 0; nt < 4; ++nt) a1[nt] = (fx4){0.f,0.f,0.f,0.f};
        #pragma unroll
        for (int ks = 0; ks < 3; ++ks) {
            #pragma unroll
            for (int nt = 0; nt < 4; ++nt) {
                s8v b = *reinterpret_cast<const s8v*>(&W1c[(nt*16 + l15)*LDH + ks*32 + g4*8]);
                a1[nt] = MFMA16(ha[ks], b, a1[nt]);
            }
        }
        // gelu^2 -> Ac (wave-private rows: no barrier before fc2)
        #pragma unroll
        for (int nt = 0; nt < 4; ++nt) {
            const float bb = bf1[ck * 64 + nt * 16 + l15];
            #pragma unroll
            for (int r = 0; r < 4; ++r) {
                float v0 = a1[nt][r] + bb;
                Ac[(wave*16 + g4*4 + r) * LDA + nt*16 + l15] = f2bf(gelu_t(gelu_t(v0)));
            }
        }
        // fc2
        #pragma unroll
        for (int ks = 0; ks < 2; ++ks) {
            s8v a = *reinterpret_cast<const s8v*>(&Ac[(wave*16 + l15)*LDA + ks*32 + g4*8]);
            #pragma unroll
            for (int nt = 0; nt < 6; ++nt) {
                s8v b = *reinterpret_cast<const s8v*>(&W2c[(nt*16 + l15)*LDA + ks*32 + g4*8]);
                oacc[nt] = MFMA16(a, b, oacc[nt]);
            }
        }
        __syncthreads();
        if (ck < 5) {
            K3_ST(tid, n0); K3_ST(tid + 512, n1); K3_ST(tid + 1024, n2);
            __syncthreads();
        }
    }

    const int rowb = blk * 128 + wave * 16 + g4 * 4;
    #pragma unroll
    for (int nt = 0; nt < 6; ++nt) {
        const int col = nt * 16 + l15;
        const float bb = bf2[col];
        #pragma unroll
        for (int r = 0; r < 4; ++r) {
            const size_t idx = (size_t)(rowb + r) * CC + col;
            xio[idx] = xio[idx] + oacc[nt][r] + bb;
        }
    }
}

extern "C" void kernel_launch(void* const* d_in, const int* in_sizes, int n_in,
                              void* d_out, int out_size, void* d_ws, size_t ws_size,
                              hipStream_t stream)
{
    const float* x    = (const float*)d_in[0];
    const float* n1g  = (const float*)d_in[1];
    const float* n1b  = (const float*)d_in[2];
    const float* qw   = (const float*)d_in[3];
    const float* qb   = (const float*)d_in[4];
    const float* btab = (const float*)d_in[5];
    const float* pw   = (const float*)d_in[6];
    const float* pb   = (const float*)d_in[7];
    const float* n2g  = (const float*)d_in[8];
    const float* n2b  = (const float*)d_in[9];
    const float* w1   = (const float*)d_in[10];
    const float* bf1  = (const float*)d_in[11];
    const float* w2   = (const float*)d_in[12];
    const float* bf2  = (const float*)d_in[13];
    float* out = (float*)d_out;

    unsigned short* qkvb = (unsigned short*)d_ws;                 // TOT*288 bf16 = 57.8 MB
    unsigned short* wbf = qkvb + (size_t)TOT * 288;
    unsigned short* qwt = wbf;
    unsigned short* pwt = qwt + 288 * 96;
    unsigned short* w1t = pwt + 96 * 96;
    unsigned short* w2t = w1t + 384 * 96;
    float* bmt = (float*)(wbf + 110592);                          // [4][3][49][64]

    p0_prep <<<579, 256, 0, stream>>>(qw, pw, w1, w2, btab, wbf);
    k1_qkv  <<<TOT/128, 512, 0, stream>>>(x, n1g, n1b, qwt, qb, qkvb);
    k2_attn <<<BB*NWIN*NHD, 64, 0, stream>>>(qkvb, bmt);
    k2b_proj<<<TOT/128, 512, 0, stream>>>(qkvb, pwt, pb, x, out);
    k3_mlp  <<<TOT/128, 512, 0, stream>>>(out, n2g, n2b, w1t, bf1, w2t, bf2);
}